// Round 3
// baseline (1046.945 us; speedup 1.0000x reference)
//
#include <hip/hip_runtime.h>
#include <math.h>

#define C 128
#define K 16

typedef unsigned short ushort_t;
typedef unsigned int u32;
typedef float f32x4 __attribute__((ext_vector_type(4)));
typedef _Float16 f16x8 __attribute__((ext_vector_type(8)));

union U8h { _Float16 h[8]; uint4 u; };

__device__ __forceinline__ float f16tof(ushort_t b) {
    _Float16 h = __builtin_bit_cast(_Float16, b); return (float)h;
}
__device__ __forceinline__ ushort_t ftof16(float f) {
    _Float16 h = (_Float16)f; return __builtin_bit_cast(ushort_t, h);
}
__device__ __forceinline__ f32x4 mfma16(f16x8 a, f16x8 b, f32x4 c) {
    return __builtin_amdgcn_mfma_f32_16x16x32_f16(a, b, c, 0, 0, 0);
}

// ---------------------------------------------------------------------------
// Prep: transpose+convert 4 weight matrices fp32 -> fp16, WT[n][e] layout.
// ---------------------------------------------------------------------------
__global__ __launch_bounds__(128) void k_prep(
    const float* __restrict__ s0, const float* __restrict__ s1,
    const float* __restrict__ s2, const float* __restrict__ s3,
    ushort_t* __restrict__ d0, ushort_t* __restrict__ d1,
    ushort_t* __restrict__ d2, ushort_t* __restrict__ d3)
{
    const int m = blockIdx.x >> 7, n = blockIdx.x & 127, e = threadIdx.x;
    const float* s = (m==0) ? s0 : (m==1) ? s1 : (m==2) ? s2 : s3;
    ushort_t*   d = (m==0) ? d0 : (m==1) ? d1 : (m==2) ? d2 : d3;
    d[n*C + e] = ftof16(s[e*C + n]);
}

// ---------------------------------------------------------------------------
// Kernel 1: h = x@W_top + b; phi/psi/alpha = h@W_* + b   via f16 MFMA.
// 512 thr / 8 waves; wave w owns cols [16w,16w+16); 64 rows per block.
// ---------------------------------------------------------------------------
__global__ __launch_bounds__(512) void k_qkv2(
    const float* __restrict__ x,
    const ushort_t* __restrict__ WTt, const float* __restrict__ bt,
    const ushort_t* __restrict__ WTp, const float* __restrict__ bp,
    const ushort_t* __restrict__ WTs, const float* __restrict__ bs,
    const ushort_t* __restrict__ WTa, const float* __restrict__ ba,
    ushort_t* __restrict__ phiB, ushort_t* __restrict__ psiB,
    ushort_t* __restrict__ alfB)
{
    __shared__ ushort_t sX[64*C];
    __shared__ ushort_t sH[64*C];
    const int tid = threadIdx.x, lane = tid & 63, wv = tid >> 6;
    const int ncol = (wv<<4) + (lane&15), arow = lane&15;
    const int kgrp = lane>>4, krow0 = kgrp<<3;
    const int r0 = blockIdx.x * 64;

    // stage x -> f16, swizzled
    {
        const int rX = tid>>3, cX = (tid&7)<<4;
        const float* xp = &x[(size_t)(r0+rX)*C + cX];
        #pragma unroll
        for (int hf = 0; hf < 2; ++hf) {
            const float4 a  = *(const float4*)&xp[hf*8 + 0];
            const float4 b2 = *(const float4*)&xp[hf*8 + 4];
            U8h v;
            v.h[0]=(_Float16)a.x;  v.h[1]=(_Float16)a.y;
            v.h[2]=(_Float16)a.z;  v.h[3]=(_Float16)a.w;
            v.h[4]=(_Float16)b2.x; v.h[5]=(_Float16)b2.y;
            v.h[6]=(_Float16)b2.z; v.h[7]=(_Float16)b2.w;
            const int col = cX + hf*8;
            *(uint4*)&sX[(rX<<7) + (col ^ ((rX&7)<<3))] = v.u;
        }
    }
    __syncthreads();

    // ---- h = x @ Wt + bt -> sH (f16, swizzled, pair-packed writes)
    {
        f16x8 bf[4]; f32x4 hacc[4];
        #pragma unroll
        for (int kk = 0; kk < 4; ++kk)
            bf[kk] = *(const f16x8*)&WTt[(size_t)ncol*C + (kk<<5) + krow0];
        #pragma unroll
        for (int m = 0; m < 4; ++m) hacc[m] = (f32x4){0.f,0.f,0.f,0.f};
        __builtin_amdgcn_s_setprio(1);
        #pragma unroll
        for (int m = 0; m < 4; ++m)
            #pragma unroll
            for (int kk = 0; kk < 4; ++kk) {
                const int row = (m<<4) + arow;
                const f16x8 af = *(const f16x8*)&sX[(row<<7) + (((kk<<5)+krow0) ^ ((arow&7)<<3))];
                hacc[m] = mfma16(af, bf[kk], hacc[m]);
            }
        __builtin_amdgcn_s_setprio(0);
        const float btc = bt[ncol];
        #pragma unroll
        for (int m = 0; m < 4; ++m)
            #pragma unroll
            for (int r = 0; r < 4; ++r) {
                const int row = (m<<4) + (kgrp<<2) + r;
                const u32 hv = ftof16(hacc[m][r] + btc);
                const u32 pv = (u32)__shfl_xor((int)hv, 1);
                if (!(lane&1))
                    *(u32*)&sH[(row<<7) + (ncol ^ ((row&7)<<3))] = hv | (pv<<16);
            }
    }
    __syncthreads();

    // ---- phi / psi / alpha GEMMs
#define OGEMM(WT_, b_, o_)                                                    \
    {                                                                         \
        f16x8 wf[4]; f32x4 oacc[4];                                           \
        _Pragma("unroll")                                                     \
        for (int kk = 0; kk < 4; ++kk)                                        \
            wf[kk] = *(const f16x8*)&WT_[(size_t)ncol*C + (kk<<5) + krow0];   \
        _Pragma("unroll")                                                     \
        for (int m = 0; m < 4; ++m) oacc[m] = (f32x4){0.f,0.f,0.f,0.f};      \
        __builtin_amdgcn_s_setprio(1);                                        \
        _Pragma("unroll")                                                     \
        for (int m = 0; m < 4; ++m)                                           \
            _Pragma("unroll")                                                 \
            for (int kk = 0; kk < 4; ++kk) {                                  \
                const int row = (m<<4) + arow;                                \
                const f16x8 af = *(const f16x8*)&sH[(row<<7) + (((kk<<5)+krow0) ^ ((arow&7)<<3))]; \
                oacc[m] = mfma16(af, wf[kk], oacc[m]);                        \
            }                                                                 \
        __builtin_amdgcn_s_setprio(0);                                        \
        const float bc = b_[ncol];                                            \
        _Pragma("unroll")                                                     \
        for (int m = 0; m < 4; ++m)                                           \
            _Pragma("unroll")                                                 \
            for (int r = 0; r < 4; ++r) {                                     \
                const int row = (m<<4) + (kgrp<<2) + r;                       \
                const u32 hv = ftof16(oacc[m][r] + bc);                       \
                const u32 pv = (u32)__shfl_xor((int)hv, 1);                   \
                if (!(lane&1))                                                \
                    *(u32*)&o_[(size_t)(r0+row)*C + ncol] = hv | (pv<<16);    \
            }                                                                 \
    }
    OGEMM(WTp, bp, phiB)
    OGEMM(WTs, bs, psiB)
    OGEMM(WTa, ba, alfB)
#undef OGEMM
}

// ---------------------------------------------------------------------------
// Kernel 2: fused vector attention, 2 points per iteration (A-tiles 32x128).
// 512 thr / 8 waves; wave w owns cols [16w,16w+16); hi/lo f16 split MFMA.
// ---------------------------------------------------------------------------
__global__ __launch_bounds__(512, 4) void k_attn3(
    const ushort_t* __restrict__ phiB, const ushort_t* __restrict__ psiB,
    const ushort_t* __restrict__ alfB,
    const float* __restrict__ coords, const int* __restrict__ nidx,
    const float* __restrict__ Wd1, const float* __restrict__ bd1,
    const ushort_t* __restrict__ WTd2, const float* __restrict__ bd2,
    const ushort_t* __restrict__ WTg1, const float* __restrict__ bg1,
    const ushort_t* __restrict__ WTg2,
    const ushort_t* __restrict__ WTdn, const float* __restrict__ bdn,
    const float* __restrict__ x, float* __restrict__ out,
    int npairs, int ppb)
{
    __shared__ ushort_t sTU[2][32*C];      // t1, then u (aliased across S2)
    __shared__ ushort_t sA[2][32*C];       // attn_in
    __shared__ ushort_t sPsi[32][136], sAlf[32][136];
    __shared__ ushort_t sPhi[2][2*C];
    __shared__ float    sY[2][C];
    __shared__ float    sRel[2][32][3];
    __shared__ int      sIdx[2][32];
    __shared__ float    sWd1[3][C];
    __shared__ float    sbd1[C];

    const int tid = threadIdx.x, lane = tid & 63, wv = tid >> 6;
    const int ncol = (wv<<4) + (lane&15), arow = lane&15;
    const int kgrp = lane>>4, krow0 = kgrp<<3;
    const int r_g = tid>>4, c8 = (tid&15)<<3;

    if (tid < 3*C) ((float*)sWd1)[tid] = Wd1[tid];
    else if (tid < 4*C) sbd1[tid - 3*C] = bd1[tid - 3*C];

    // persistent weight fragments
    f16x8 wd2[4], wg1[4], wg2[4], wdn[4];
    #pragma unroll
    for (int kk = 0; kk < 4; ++kk) {
        wd2[kk] = *(const f16x8*)&WTd2[(size_t)ncol*C + (kk<<5) + krow0];
        wg1[kk] = *(const f16x8*)&WTg1[(size_t)ncol*C + (kk<<5) + krow0];
        wg2[kk] = *(const f16x8*)&WTg2[(size_t)ncol*C + (kk<<5) + krow0];
    }
    #pragma unroll
    for (int z = 0; z < 4; ++z)
        wdn[z] = *(const f16x8*)&WTdn[(size_t)ncol*C + (kgrp<<5) + (z<<3)];
    const float bd2c = bd2[ncol], bg1c = bg1[ncol], bdnc = bdn[ncol];

    const int q0 = blockIdx.x * ppb;
    if (q0 >= npairs) return;
    const int qend = (q0 + ppb < npairs) ? (q0 + ppb) : npairs;

    // prologue: pair q0 idx/rel/phi
    if (tid < 32) {
        const int pt = q0*2 + (tid>>4);
        const int j = nidx[(size_t)pt*K + (tid&15)];
        sIdx[0][tid] = j;
        sRel[0][tid][0] = coords[(size_t)pt*3+0] - coords[(size_t)j*3+0];
        sRel[0][tid][1] = coords[(size_t)pt*3+1] - coords[(size_t)j*3+1];
        sRel[0][tid][2] = coords[(size_t)pt*3+2] - coords[(size_t)j*3+2];
    } else if (tid >= 64 && tid < 128) {
        const int i = tid - 64, pt = q0*2 + (i>>5), o = (i&31)<<2;
        *(uint2*)&sPhi[0][((i>>5)<<7) + o] = *(const uint2*)&phiB[(size_t)pt*C + o];
    }
    __syncthreads();
    uint4 stPsi, stAlf;
    {
        const int j = sIdx[0][r_g];
        stPsi = *(const uint4*)&psiB[(size_t)j*C + c8];
        stAlf = *(const uint4*)&alfB[(size_t)j*C + c8];
    }

    int idxReg = 0; uint2 phiReg = {0,0};
    float cn0=0,cn1=0,cn2=0,cj0=0,cj1=0,cj2=0;

    for (int q = q0; q < qend; ++q) {
        const int b = q & 1, b2 = b ^ 1;
        const bool hn = (q + 1 < qend);

        // 1: commit staged gathers
        *(uint4*)&sPsi[r_g][c8] = stPsi;
        *(uint4*)&sAlf[r_g][c8] = stAlf;

        // 2: prefetch next-pair idx / own coords / phi
        if (hn) {
            if (tid < 32) {
                const int pt = (q+1)*2 + (tid>>4);
                idxReg = nidx[(size_t)pt*K + (tid&15)];
                cn0 = coords[(size_t)pt*3+0];
                cn1 = coords[(size_t)pt*3+1];
                cn2 = coords[(size_t)pt*3+2];
            } else if (tid >= 64 && tid < 128) {
                const int i = tid - 64, pt = (q+1)*2 + (i>>5), o = (i&31)<<2;
                phiReg = *(const uint2*)&phiB[(size_t)pt*C + o];
            }
        }

        // 3: t1 = relu(rel @ Wd1 + bd1) -> hi/lo
        {
            const float r0v = sRel[b][r_g][0], r1v = sRel[b][r_g][1], r2v = sRel[b][r_g][2];
            U8h hi, lo;
            #pragma unroll
            for (int z = 0; z < 8; ++z) {
                float t = fmaf(r0v, sWd1[0][c8+z],
                          fmaf(r1v, sWd1[1][c8+z],
                          fmaf(r2v, sWd1[2][c8+z], sbd1[c8+z])));
                t = fmaxf(t, 0.f);
                hi.h[z] = (_Float16)t;
                lo.h[z] = (_Float16)(t - (float)hi.h[z]);
            }
            const int si = (r_g<<7) + (c8 ^ ((r_g&7)<<3));
            *(uint4*)&sTU[0][si] = hi.u;
            *(uint4*)&sTU[1][si] = lo.u;
        }
        __syncthreads();                                   // S1

        // 5: pos = t1 @ Wd2 + bd2
        f32x4 pos[2];
        #pragma unroll
        for (int m = 0; m < 2; ++m) pos[m] = (f32x4){0.f,0.f,0.f,0.f};
        __builtin_amdgcn_s_setprio(1);
        #pragma unroll
        for (int m = 0; m < 2; ++m)
            #pragma unroll
            for (int kk = 0; kk < 4; ++kk) {
                const int si = (((m<<4)+arow)<<7) + (((kk<<5)+krow0) ^ ((arow&7)<<3));
                pos[m] = mfma16(*(const f16x8*)&sTU[0][si], wd2[kk], pos[m]);
                pos[m] = mfma16(*(const f16x8*)&sTU[1][si], wd2[kk], pos[m]);
            }
        __builtin_amdgcn_s_setprio(0);
        #pragma unroll
        for (int m = 0; m < 2; ++m)
            #pragma unroll
            for (int z = 0; z < 4; ++z) pos[m][z] += bd2c;

        // 6: attn_in = phi - psi + pos -> sA (pair-packed u32 writes)
        #pragma unroll
        for (int m = 0; m < 2; ++m) {
            const float phic = f16tof(sPhi[b][(m<<7) + ncol]);
            #pragma unroll
            for (int r = 0; r < 4; ++r) {
                const int row = (m<<4) + (kgrp<<2) + r;
                const float av = phic - f16tof(sPsi[row][ncol]) + pos[m][r];
                const _Float16 h = (_Float16)av;
                const u32 hv = __builtin_bit_cast(ushort_t, h);
                const u32 lv = ftof16(av - (float)h);
                const u32 hp = (u32)__shfl_xor((int)hv, 1);
                const u32 lp = (u32)__shfl_xor((int)lv, 1);
                if (!(lane&1)) {
                    const int si = (row<<7) + (ncol ^ ((row&7)<<3));
                    *(u32*)&sA[0][si] = hv | (hp<<16);
                    *(u32*)&sA[1][si] = lv | (lp<<16);
                }
            }
        }

        // 7: stash next idx/phi; issue coords[j]
        if (hn) {
            if (tid < 32) {
                sIdx[b2][tid] = idxReg;
                cj0 = coords[(size_t)idxReg*3+0];
                cj1 = coords[(size_t)idxReg*3+1];
                cj2 = coords[(size_t)idxReg*3+2];
            } else if (tid >= 64 && tid < 128) {
                const int i = tid - 64;
                *(uint2*)&sPhi[b2][((i>>5)<<7) + ((i&31)<<2)] = phiReg;
            }
        }
        __syncthreads();                                   // S2

        // 9: u = relu(attn @ Wg1 + bg1) -> sTU (aliased; safe across S2)
        {
            f32x4 ua[2];
            #pragma unroll
            for (int m = 0; m < 2; ++m) ua[m] = (f32x4){0.f,0.f,0.f,0.f};
            __builtin_amdgcn_s_setprio(1);
            #pragma unroll
            for (int m = 0; m < 2; ++m)
                #pragma unroll
                for (int kk = 0; kk < 4; ++kk) {
                    const int si = (((m<<4)+arow)<<7) + (((kk<<5)+krow0) ^ ((arow&7)<<3));
                    ua[m] = mfma16(*(const f16x8*)&sA[0][si], wg1[kk], ua[m]);
                    ua[m] = mfma16(*(const f16x8*)&sA[1][si], wg1[kk], ua[m]);
                }
            __builtin_amdgcn_s_setprio(0);
            #pragma unroll
            for (int m = 0; m < 2; ++m)
                #pragma unroll
                for (int r = 0; r < 4; ++r) {
                    const int row = (m<<4) + (kgrp<<2) + r;
                    const float uv = fmaxf(ua[m][r] + bg1c, 0.f);
                    const _Float16 h = (_Float16)uv;
                    const u32 hv = __builtin_bit_cast(ushort_t, h);
                    const u32 lv = ftof16(uv - (float)h);
                    const u32 hp = (u32)__shfl_xor((int)hv, 1);
                    const u32 lp = (u32)__shfl_xor((int)lv, 1);
                    if (!(lane&1)) {
                        const int si = (row<<7) + (ncol ^ ((row&7)<<3));
                        *(u32*)&sTU[0][si] = hv | (hp<<16);
                        *(u32*)&sTU[1][si] = lv | (lp<<16);
                    }
                }
        }
        __syncthreads();                                   // S3

        // 11: logits = u @ Wg2 (b_g2 dropped: softmax shift-invariant)
        f32x4 lg[2];
        #pragma unroll
        for (int m = 0; m < 2; ++m) lg[m] = (f32x4){0.f,0.f,0.f,0.f};
        __builtin_amdgcn_s_setprio(1);
        #pragma unroll
        for (int m = 0; m < 2; ++m)
            #pragma unroll
            for (int kk = 0; kk < 4; ++kk) {
                const int si = (((m<<4)+arow)<<7) + (((kk<<5)+krow0) ^ ((arow&7)<<3));
                lg[m] = mfma16(*(const f16x8*)&sTU[0][si], wg2[kk], lg[m]);
                lg[m] = mfma16(*(const f16x8*)&sTU[1][si], wg2[kk], lg[m]);
            }
        __builtin_amdgcn_s_setprio(0);

        // 12-13: softmax over K per point; y
        #pragma unroll
        for (int m = 0; m < 2; ++m) {
            float mx = fmaxf(fmaxf(lg[m][0], lg[m][1]), fmaxf(lg[m][2], lg[m][3]));
            mx = fmaxf(mx, __shfl_xor(mx, 16));
            mx = fmaxf(mx, __shfl_xor(mx, 32));
            const float e0 = __expf(lg[m][0]-mx), e1 = __expf(lg[m][1]-mx);
            const float e2 = __expf(lg[m][2]-mx), e3 = __expf(lg[m][3]-mx);
            float den = e0 + e1 + e2 + e3;
            den += __shfl_xor(den, 16);
            den += __shfl_xor(den, 32);
            const float inv = 1.0f / den;
            const int rr0 = (m<<4) + (kgrp<<2);
            float yp;
            yp  = e0 * (f16tof(sAlf[rr0+0][ncol]) + pos[m][0]);
            yp += e1 * (f16tof(sAlf[rr0+1][ncol]) + pos[m][1]);
            yp += e2 * (f16tof(sAlf[rr0+2][ncol]) + pos[m][2]);
            yp += e3 * (f16tof(sAlf[rr0+3][ncol]) + pos[m][3]);
            yp *= inv;
            yp += __shfl_xor(yp, 16);
            yp += __shfl_xor(yp, 32);
            if (lane < 16) sY[m][ncol] = yp;
        }

        // 14: stage next-pair gathers; rel for next pair
        if (hn) {
            const int j = sIdx[b2][r_g];
            stPsi = *(const uint4*)&psiB[(size_t)j*C + c8];
            stAlf = *(const uint4*)&alfB[(size_t)j*C + c8];
            if (tid < 32) {
                sRel[b2][tid][0] = cn0 - cj0;
                sRel[b2][tid][1] = cn1 - cj1;
                sRel[b2][tid][2] = cn2 - cj2;
            }
        }
        __syncthreads();                                   // S4

        // 16: out = y @ W_down + b_down + x  (2 points)
        #pragma unroll
        for (int m = 0; m < 2; ++m) {
            float acc = 0.f;
            const int e0i = kgrp << 5;
            #pragma unroll
            for (int z = 0; z < 4; ++z) {
                const float4 ya = *(const float4*)&sY[m][e0i + (z<<3)];
                const float4 yb = *(const float4*)&sY[m][e0i + (z<<3) + 4];
                const f16x8 w8 = wdn[z];
                acc = fmaf(ya.x, (float)w8[0], acc);
                acc = fmaf(ya.y, (float)w8[1], acc);
                acc = fmaf(ya.z, (float)w8[2], acc);
                acc = fmaf(ya.w, (float)w8[3], acc);
                acc = fmaf(yb.x, (float)w8[4], acc);
                acc = fmaf(yb.y, (float)w8[5], acc);
                acc = fmaf(yb.z, (float)w8[6], acc);
                acc = fmaf(yb.w, (float)w8[7], acc);
            }
            acc += __shfl_xor(acc, 16);
            acc += __shfl_xor(acc, 32);
            if (lane < 16) {
                const size_t p = (size_t)(q*2 + m);
                out[p*C + ncol] = acc + bdnc + x[p*C + ncol];
            }
        }
    }
}

// ---------------------------------------------------------------------------
extern "C" void kernel_launch(void* const* d_in, const int* in_sizes, int n_in,
                              void* d_out, int out_size, void* d_ws, size_t ws_size,
                              hipStream_t stream)
{
    const float* x      = (const float*)d_in[0];
    const float* coords = (const float*)d_in[1];
    const int*   nidx   = (const int*)d_in[2];
    const float* W_top  = (const float*)d_in[3];
    const float* b_top  = (const float*)d_in[4];
    const float* W_down = (const float*)d_in[5];
    const float* b_down = (const float*)d_in[6];
    const float* W_phi  = (const float*)d_in[7];
    const float* b_phi  = (const float*)d_in[8];
    const float* W_psi  = (const float*)d_in[9];
    const float* b_psi  = (const float*)d_in[10];
    const float* W_alpha= (const float*)d_in[11];
    const float* b_alpha= (const float*)d_in[12];
    const float* W_d1   = (const float*)d_in[13];
    const float* b_d1   = (const float*)d_in[14];
    const float* W_d2   = (const float*)d_in[15];
    const float* b_d2   = (const float*)d_in[16];
    const float* W_g1   = (const float*)d_in[17];
    const float* b_g1   = (const float*)d_in[18];
    const float* W_g2   = (const float*)d_in[19];
    const float* b_g2   = (const float*)d_in[20];
    (void)b_g2; // softmax shift-invariant

    const int N = in_sizes[0] / C;

    ushort_t* WTt  = (ushort_t*)d_ws;
    ushort_t* WTp  = WTt  + C*C;
    ushort_t* WTs  = WTp  + C*C;
    ushort_t* WTa  = WTs  + C*C;
    ushort_t* WTd2 = WTa  + C*C;
    ushort_t* WTg1 = WTd2 + C*C;
    ushort_t* WTg2 = WTg1 + C*C;
    ushort_t* WTdn = WTg2 + C*C;
    ushort_t* phiB = WTdn + C*C;
    ushort_t* psiB = phiB + (size_t)N*C;
    ushort_t* alfB = psiB + (size_t)N*C;
    float* out = (float*)d_out;

    hipLaunchKernelGGL(k_prep, dim3(4*C), dim3(C), 0, stream,
        W_top, W_phi, W_psi, W_alpha, WTt, WTp, WTs, WTa);
    hipLaunchKernelGGL(k_prep, dim3(4*C), dim3(C), 0, stream,
        W_d2, W_g1, W_g2, W_down, WTd2, WTg1, WTg2, WTdn);

    hipLaunchKernelGGL(k_qkv2, dim3(N / 64), dim3(512), 0, stream,
        x, WTt, b_top, WTp, b_phi, WTs, b_psi, WTa, b_alpha,
        phiB, psiB, alfB);

    const int npairs = N / 2;
    const int NBLK = 4096;
    const int ppb = (npairs + NBLK - 1) / NBLK;
    hipLaunchKernelGGL(k_attn3, dim3(NBLK), dim3(512), 0, stream,
        phiB, psiB, alfB, coords, nidx,
        W_d1, b_d1, WTd2, b_d2, WTg1, b_g1, WTg2,
        WTdn, b_down, x, out, npairs, ppb);
}

// Round 4
// 730.154 us; speedup vs baseline: 1.4339x; 1.4339x over previous
//
#include <hip/hip_runtime.h>
#include <math.h>

#define C 128
#define K 16

typedef unsigned short ushort_t;
typedef unsigned int u32;
typedef float f32x4 __attribute__((ext_vector_type(4)));
typedef _Float16 f16x8 __attribute__((ext_vector_type(8)));

union U8h { _Float16 h[8]; uint4 u; };

__device__ __forceinline__ float f16tof(ushort_t b) {
    _Float16 h = __builtin_bit_cast(_Float16, b); return (float)h;
}
__device__ __forceinline__ ushort_t ftof16(float f) {
    _Float16 h = (_Float16)f; return __builtin_bit_cast(ushort_t, h);
}
__device__ __forceinline__ f32x4 mfma16(f16x8 a, f16x8 b, f32x4 c) {
    return __builtin_amdgcn_mfma_f32_16x16x32_f16(a, b, c, 0, 0, 0);
}

// ---------------------------------------------------------------------------
// Prep: transpose+convert 4 weight matrices fp32 -> fp16, WT[n][e] layout.
// ---------------------------------------------------------------------------
__global__ __launch_bounds__(128) void k_prep(
    const float* __restrict__ s0, const float* __restrict__ s1,
    const float* __restrict__ s2, const float* __restrict__ s3,
    ushort_t* __restrict__ d0, ushort_t* __restrict__ d1,
    ushort_t* __restrict__ d2, ushort_t* __restrict__ d3)
{
    const int m = blockIdx.x >> 7, n = blockIdx.x & 127, e = threadIdx.x;
    const float* s = (m==0) ? s0 : (m==1) ? s1 : (m==2) ? s2 : s3;
    ushort_t*   d = (m==0) ? d0 : (m==1) ? d1 : (m==2) ? d2 : d3;
    d[n*C + e] = ftof16(s[e*C + n]);
}

// ---------------------------------------------------------------------------
// Kernel 1: h = x@W_top + b; phi/psi/alpha = h@W_* + b   via f16 MFMA.
// 512 thr / 8 waves; wave w owns cols [16w,16w+16); 64 rows per block.
// ---------------------------------------------------------------------------
__global__ __launch_bounds__(512) void k_qkv2(
    const float* __restrict__ x,
    const ushort_t* __restrict__ WTt, const float* __restrict__ bt,
    const ushort_t* __restrict__ WTp, const float* __restrict__ bp,
    const ushort_t* __restrict__ WTs, const float* __restrict__ bs,
    const ushort_t* __restrict__ WTa, const float* __restrict__ ba,
    ushort_t* __restrict__ phiB, ushort_t* __restrict__ psiB,
    ushort_t* __restrict__ alfB)
{
    __shared__ ushort_t sX[64*C];
    __shared__ ushort_t sH[64*C];
    const int tid = threadIdx.x, lane = tid & 63, wv = tid >> 6;
    const int ncol = (wv<<4) + (lane&15), arow = lane&15;
    const int kgrp = lane>>4, krow0 = kgrp<<3;
    const int r0 = blockIdx.x * 64;

    // stage x -> f16, swizzled
    {
        const int rX = tid>>3, cX = (tid&7)<<4;
        const float* xp = &x[(size_t)(r0+rX)*C + cX];
        #pragma unroll
        for (int hf = 0; hf < 2; ++hf) {
            const float4 a  = *(const float4*)&xp[hf*8 + 0];
            const float4 b2 = *(const float4*)&xp[hf*8 + 4];
            U8h v;
            v.h[0]=(_Float16)a.x;  v.h[1]=(_Float16)a.y;
            v.h[2]=(_Float16)a.z;  v.h[3]=(_Float16)a.w;
            v.h[4]=(_Float16)b2.x; v.h[5]=(_Float16)b2.y;
            v.h[6]=(_Float16)b2.z; v.h[7]=(_Float16)b2.w;
            const int col = cX + hf*8;
            *(uint4*)&sX[(rX<<7) + (col ^ ((rX&7)<<3))] = v.u;
        }
    }
    __syncthreads();

    // ---- h = x @ Wt + bt -> sH (f16, swizzled, pair-packed writes)
    {
        f16x8 bf[4]; f32x4 hacc[4];
        #pragma unroll
        for (int kk = 0; kk < 4; ++kk)
            bf[kk] = *(const f16x8*)&WTt[(size_t)ncol*C + (kk<<5) + krow0];
        #pragma unroll
        for (int m = 0; m < 4; ++m) hacc[m] = (f32x4){0.f,0.f,0.f,0.f};
        __builtin_amdgcn_s_setprio(1);
        #pragma unroll
        for (int m = 0; m < 4; ++m)
            #pragma unroll
            for (int kk = 0; kk < 4; ++kk) {
                const int row = (m<<4) + arow;
                const f16x8 af = *(const f16x8*)&sX[(row<<7) + (((kk<<5)+krow0) ^ ((arow&7)<<3))];
                hacc[m] = mfma16(af, bf[kk], hacc[m]);
            }
        __builtin_amdgcn_s_setprio(0);
        const float btc = bt[ncol];
        #pragma unroll
        for (int m = 0; m < 4; ++m)
            #pragma unroll
            for (int r = 0; r < 4; ++r) {
                const int row = (m<<4) + (kgrp<<2) + r;
                const u32 hv = ftof16(hacc[m][r] + btc);
                const u32 pv = (u32)__shfl_xor((int)hv, 1);
                if (!(lane&1))
                    *(u32*)&sH[(row<<7) + (ncol ^ ((row&7)<<3))] = hv | (pv<<16);
            }
    }
    __syncthreads();

    // ---- phi / psi / alpha GEMMs
#define OGEMM(WT_, b_, o_)                                                    \
    {                                                                         \
        f16x8 wf[4]; f32x4 oacc[4];                                           \
        _Pragma("unroll")                                                     \
        for (int kk = 0; kk < 4; ++kk)                                        \
            wf[kk] = *(const f16x8*)&WT_[(size_t)ncol*C + (kk<<5) + krow0];   \
        _Pragma("unroll")                                                     \
        for (int m = 0; m < 4; ++m) oacc[m] = (f32x4){0.f,0.f,0.f,0.f};      \
        __builtin_amdgcn_s_setprio(1);                                        \
        _Pragma("unroll")                                                     \
        for (int m = 0; m < 4; ++m)                                           \
            _Pragma("unroll")                                                 \
            for (int kk = 0; kk < 4; ++kk) {                                  \
                const int row = (m<<4) + arow;                                \
                const f16x8 af = *(const f16x8*)&sH[(row<<7) + (((kk<<5)+krow0) ^ ((arow&7)<<3))]; \
                oacc[m] = mfma16(af, wf[kk], oacc[m]);                        \
            }                                                                 \
        __builtin_amdgcn_s_setprio(0);                                        \
        const float bc = b_[ncol];                                            \
        _Pragma("unroll")                                                     \
        for (int m = 0; m < 4; ++m)                                           \
            _Pragma("unroll")                                                 \
            for (int r = 0; r < 4; ++r) {                                     \
                const int row = (m<<4) + (kgrp<<2) + r;                       \
                const u32 hv = ftof16(oacc[m][r] + bc);                       \
                const u32 pv = (u32)__shfl_xor((int)hv, 1);                   \
                if (!(lane&1))                                                \
                    *(u32*)&o_[(size_t)(r0+row)*C + ncol] = hv | (pv<<16);    \
            }                                                                 \
    }
    OGEMM(WTp, bp, phiB)
    OGEMM(WTs, bs, psiB)
    OGEMM(WTa, ba, alfB)
#undef OGEMM
}

// ---------------------------------------------------------------------------
// Kernel 2: fused vector attention, 2 points per iteration (A-tiles 32x128).
// 512 thr / 8 waves; wave w owns cols [16w,16w+16); hi/lo f16 split MFMA.
// Gathers issued ~3 phases before commit; x prefetched at iter start.
// ---------------------------------------------------------------------------
__global__ __launch_bounds__(512, 2) void k_attn3(
    const ushort_t* __restrict__ phiB, const ushort_t* __restrict__ psiB,
    const ushort_t* __restrict__ alfB,
    const float* __restrict__ coords, const int* __restrict__ nidx,
    const float* __restrict__ Wd1, const float* __restrict__ bd1,
    const ushort_t* __restrict__ WTd2, const float* __restrict__ bd2,
    const ushort_t* __restrict__ WTg1, const float* __restrict__ bg1,
    const ushort_t* __restrict__ WTg2,
    const ushort_t* __restrict__ WTdn, const float* __restrict__ bdn,
    const float* __restrict__ x, float* __restrict__ out,
    int npairs, int ppb)
{
    __shared__ ushort_t sTU[2][32*C];      // t1, then u (aliased across S2)
    __shared__ ushort_t sA[2][32*C];       // attn_in
    __shared__ ushort_t sPsi[32][136], sAlf[32][136];
    __shared__ ushort_t sPhi[2][2*C];
    __shared__ float    sY[2][C];
    __shared__ float    sRel[2][32][3];
    __shared__ int      sIdx[2][32];
    __shared__ float    sWd1[3][C];
    __shared__ float    sbd1[C];

    const int tid = threadIdx.x, lane = tid & 63, wv = tid >> 6;
    const int ncol = (wv<<4) + (lane&15), arow = lane&15;
    const int kgrp = lane>>4, krow0 = kgrp<<3;
    const int r_g = tid>>4, c8 = (tid&15)<<3;

    if (tid < 3*C) ((float*)sWd1)[tid] = Wd1[tid];
    else if (tid < 4*C) sbd1[tid - 3*C] = bd1[tid - 3*C];

    // persistent weight fragments
    f16x8 wd2[4], wg1[4], wg2[4], wdn[4];
    #pragma unroll
    for (int kk = 0; kk < 4; ++kk) {
        wd2[kk] = *(const f16x8*)&WTd2[(size_t)ncol*C + (kk<<5) + krow0];
        wg1[kk] = *(const f16x8*)&WTg1[(size_t)ncol*C + (kk<<5) + krow0];
        wg2[kk] = *(const f16x8*)&WTg2[(size_t)ncol*C + (kk<<5) + krow0];
    }
    #pragma unroll
    for (int z = 0; z < 4; ++z)
        wdn[z] = *(const f16x8*)&WTdn[(size_t)ncol*C + (kgrp<<5) + (z<<3)];
    const float bd2c = bd2[ncol], bg1c = bg1[ncol], bdnc = bdn[ncol];

    const int q0 = blockIdx.x * ppb;
    if (q0 >= npairs) return;
    const int qend = (q0 + ppb < npairs) ? (q0 + ppb) : npairs;

    // prologue: pair q0 idx/rel/phi
    if (tid < 32) {
        const int pt = q0*2 + (tid>>4);
        const int j = nidx[(size_t)pt*K + (tid&15)];
        sIdx[0][tid] = j;
        sRel[0][tid][0] = coords[(size_t)pt*3+0] - coords[(size_t)j*3+0];
        sRel[0][tid][1] = coords[(size_t)pt*3+1] - coords[(size_t)j*3+1];
        sRel[0][tid][2] = coords[(size_t)pt*3+2] - coords[(size_t)j*3+2];
    } else if (tid >= 64 && tid < 128) {
        const int i = tid - 64, pt = q0*2 + (i>>5), o = (i&31)<<2;
        *(uint2*)&sPhi[0][((i>>5)<<7) + o] = *(const uint2*)&phiB[(size_t)pt*C + o];
    }
    __syncthreads();
    uint4 stPsi, stAlf;
    {
        const int j = sIdx[0][r_g];
        stPsi = *(const uint4*)&psiB[(size_t)j*C + c8];
        stAlf = *(const uint4*)&alfB[(size_t)j*C + c8];
    }

    int idxReg = 0; uint2 phiReg = {0,0};
    float cn0=0,cn1=0,cn2=0,cj0=0,cj1=0,cj2=0;

    for (int q = q0; q < qend; ++q) {
        const int b = q & 1, b2 = b ^ 1;
        const bool hn = (q + 1 < qend);

        // 1: commit staged gathers (loads issued ~3 phases ago)
        *(uint4*)&sPsi[r_g][c8] = stPsi;
        *(uint4*)&sAlf[r_g][c8] = stAlf;

        // 2: prefetch next-pair idx / own coords / phi; prefetch x residual
        float xr0 = x[(size_t)(q*2+0)*C + ncol];
        float xr1 = x[(size_t)(q*2+1)*C + ncol];
        if (hn) {
            if (tid < 32) {
                const int pt = (q+1)*2 + (tid>>4);
                idxReg = nidx[(size_t)pt*K + (tid&15)];
                cn0 = coords[(size_t)pt*3+0];
                cn1 = coords[(size_t)pt*3+1];
                cn2 = coords[(size_t)pt*3+2];
            } else if (tid >= 64 && tid < 128) {
                const int i = tid - 64, pt = (q+1)*2 + (i>>5), o = (i&31)<<2;
                phiReg = *(const uint2*)&phiB[(size_t)pt*C + o];
            }
        }

        // 3: t1 = relu(rel @ Wd1 + bd1) -> hi/lo
        {
            const float r0v = sRel[b][r_g][0], r1v = sRel[b][r_g][1], r2v = sRel[b][r_g][2];
            U8h hi, lo;
            #pragma unroll
            for (int z = 0; z < 8; ++z) {
                float t = fmaf(r0v, sWd1[0][c8+z],
                          fmaf(r1v, sWd1[1][c8+z],
                          fmaf(r2v, sWd1[2][c8+z], sbd1[c8+z])));
                t = fmaxf(t, 0.f);
                hi.h[z] = (_Float16)t;
                lo.h[z] = (_Float16)(t - (float)hi.h[z]);
            }
            const int si = (r_g<<7) + (c8 ^ ((r_g&7)<<3));
            *(uint4*)&sTU[0][si] = hi.u;
            *(uint4*)&sTU[1][si] = lo.u;
        }
        __syncthreads();                                   // S1

        // 5: pos = t1 @ Wd2 + bd2
        f32x4 pos[2];
        #pragma unroll
        for (int m = 0; m < 2; ++m) pos[m] = (f32x4){0.f,0.f,0.f,0.f};
        __builtin_amdgcn_s_setprio(1);
        #pragma unroll
        for (int m = 0; m < 2; ++m)
            #pragma unroll
            for (int kk = 0; kk < 4; ++kk) {
                const int si = (((m<<4)+arow)<<7) + (((kk<<5)+krow0) ^ ((arow&7)<<3));
                pos[m] = mfma16(*(const f16x8*)&sTU[0][si], wd2[kk], pos[m]);
                pos[m] = mfma16(*(const f16x8*)&sTU[1][si], wd2[kk], pos[m]);
            }
        __builtin_amdgcn_s_setprio(0);
        #pragma unroll
        for (int m = 0; m < 2; ++m)
            #pragma unroll
            for (int z = 0; z < 4; ++z) pos[m][z] += bd2c;

        // 6: attn_in = phi - psi + pos -> sA (pair-packed u32 writes)
        #pragma unroll
        for (int m = 0; m < 2; ++m) {
            const float phic = f16tof(sPhi[b][(m<<7) + ncol]);
            #pragma unroll
            for (int r = 0; r < 4; ++r) {
                const int row = (m<<4) + (kgrp<<2) + r;
                const float av = phic - f16tof(sPsi[row][ncol]) + pos[m][r];
                const _Float16 h = (_Float16)av;
                const u32 hv = __builtin_bit_cast(ushort_t, h);
                const u32 lv = ftof16(av - (float)h);
                const u32 hp = (u32)__shfl_xor((int)hv, 1);
                const u32 lp = (u32)__shfl_xor((int)lv, 1);
                if (!(lane&1)) {
                    const int si = (row<<7) + (ncol ^ ((row&7)<<3));
                    *(u32*)&sA[0][si] = hv | (hp<<16);
                    *(u32*)&sA[1][si] = lv | (lp<<16);
                }
            }
        }

        // 7: stash next idx/phi; issue coords[j]
        if (hn) {
            if (tid < 32) {
                sIdx[b2][tid] = idxReg;
                cj0 = coords[(size_t)idxReg*3+0];
                cj1 = coords[(size_t)idxReg*3+1];
                cj2 = coords[(size_t)idxReg*3+2];
            } else if (tid >= 64 && tid < 128) {
                const int i = tid - 64;
                *(uint2*)&sPhi[b2][((i>>5)<<7) + ((i&31)<<2)] = phiReg;
            }
        }
        __syncthreads();                                   // S2

        // 8: issue next-pair psi/alpha gathers NOW (commit is next iter ph.1,
        //    ~3 phases away -> latency fully hidden under g1/g2 MFMA)
        if (hn) {
            const int j = sIdx[b2][r_g];
            stPsi = *(const uint4*)&psiB[(size_t)j*C + c8];
            stAlf = *(const uint4*)&alfB[(size_t)j*C + c8];
        }

        // 9: u = relu(attn @ Wg1 + bg1) -> sTU (aliased; safe across S2)
        {
            f32x4 ua[2];
            #pragma unroll
            for (int m = 0; m < 2; ++m) ua[m] = (f32x4){0.f,0.f,0.f,0.f};
            __builtin_amdgcn_s_setprio(1);
            #pragma unroll
            for (int m = 0; m < 2; ++m)
                #pragma unroll
                for (int kk = 0; kk < 4; ++kk) {
                    const int si = (((m<<4)+arow)<<7) + (((kk<<5)+krow0) ^ ((arow&7)<<3));
                    ua[m] = mfma16(*(const f16x8*)&sA[0][si], wg1[kk], ua[m]);
                    ua[m] = mfma16(*(const f16x8*)&sA[1][si], wg1[kk], ua[m]);
                }
            __builtin_amdgcn_s_setprio(0);
            #pragma unroll
            for (int m = 0; m < 2; ++m)
                #pragma unroll
                for (int r = 0; r < 4; ++r) {
                    const int row = (m<<4) + (kgrp<<2) + r;
                    const float uv = fmaxf(ua[m][r] + bg1c, 0.f);
                    const _Float16 h = (_Float16)uv;
                    const u32 hv = __builtin_bit_cast(ushort_t, h);
                    const u32 lv = ftof16(uv - (float)h);
                    const u32 hp = (u32)__shfl_xor((int)hv, 1);
                    const u32 lp = (u32)__shfl_xor((int)lv, 1);
                    if (!(lane&1)) {
                        const int si = (row<<7) + (ncol ^ ((row&7)<<3));
                        *(u32*)&sTU[0][si] = hv | (hp<<16);
                        *(u32*)&sTU[1][si] = lv | (lp<<16);
                    }
                }
        }
        __syncthreads();                                   // S3

        // 11: logits = u @ Wg2 (b_g2 dropped: softmax shift-invariant)
        f32x4 lg[2];
        #pragma unroll
        for (int m = 0; m < 2; ++m) lg[m] = (f32x4){0.f,0.f,0.f,0.f};
        __builtin_amdgcn_s_setprio(1);
        #pragma unroll
        for (int m = 0; m < 2; ++m)
            #pragma unroll
            for (int kk = 0; kk < 4; ++kk) {
                const int si = (((m<<4)+arow)<<7) + (((kk<<5)+krow0) ^ ((arow&7)<<3));
                lg[m] = mfma16(*(const f16x8*)&sTU[0][si], wg2[kk], lg[m]);
                lg[m] = mfma16(*(const f16x8*)&sTU[1][si], wg2[kk], lg[m]);
            }
        __builtin_amdgcn_s_setprio(0);

        // 12-13: softmax over K per point; y
        #pragma unroll
        for (int m = 0; m < 2; ++m) {
            float mx = fmaxf(fmaxf(lg[m][0], lg[m][1]), fmaxf(lg[m][2], lg[m][3]));
            mx = fmaxf(mx, __shfl_xor(mx, 16));
            mx = fmaxf(mx, __shfl_xor(mx, 32));
            const float e0 = __expf(lg[m][0]-mx), e1 = __expf(lg[m][1]-mx);
            const float e2 = __expf(lg[m][2]-mx), e3 = __expf(lg[m][3]-mx);
            float den = e0 + e1 + e2 + e3;
            den += __shfl_xor(den, 16);
            den += __shfl_xor(den, 32);
            const float inv = 1.0f / den;
            const int rr0 = (m<<4) + (kgrp<<2);
            float yp;
            yp  = e0 * (f16tof(sAlf[rr0+0][ncol]) + pos[m][0]);
            yp += e1 * (f16tof(sAlf[rr0+1][ncol]) + pos[m][1]);
            yp += e2 * (f16tof(sAlf[rr0+2][ncol]) + pos[m][2]);
            yp += e3 * (f16tof(sAlf[rr0+3][ncol]) + pos[m][3]);
            yp *= inv;
            yp += __shfl_xor(yp, 16);
            yp += __shfl_xor(yp, 32);
            if (lane < 16) sY[m][ncol] = yp;
        }

        // 14: rel for next pair (cj/cn loaded in phase 7/2)
        if (hn) {
            if (tid < 32) {
                sRel[b2][tid][0] = cn0 - cj0;
                sRel[b2][tid][1] = cn1 - cj1;
                sRel[b2][tid][2] = cn2 - cj2;
            }
        }
        __syncthreads();                                   // S4

        // 16: out = y @ W_down + b_down + x  (2 points, x prefetched)
        #pragma unroll
        for (int m = 0; m < 2; ++m) {
            float acc = 0.f;
            const int e0i = kgrp << 5;
            #pragma unroll
            for (int z = 0; z < 4; ++z) {
                const float4 ya = *(const float4*)&sY[m][e0i + (z<<3)];
                const float4 yb = *(const float4*)&sY[m][e0i + (z<<3) + 4];
                const f16x8 w8 = wdn[z];
                acc = fmaf(ya.x, (float)w8[0], acc);
                acc = fmaf(ya.y, (float)w8[1], acc);
                acc = fmaf(ya.z, (float)w8[2], acc);
                acc = fmaf(ya.w, (float)w8[3], acc);
                acc = fmaf(yb.x, (float)w8[4], acc);
                acc = fmaf(yb.y, (float)w8[5], acc);
                acc = fmaf(yb.z, (float)w8[6], acc);
                acc = fmaf(yb.w, (float)w8[7], acc);
            }
            acc += __shfl_xor(acc, 16);
            acc += __shfl_xor(acc, 32);
            if (lane < 16) {
                const size_t p = (size_t)(q*2 + m);
                out[p*C + ncol] = acc + bdnc + (m == 0 ? xr0 : xr1);
            }
        }
    }
}

// ---------------------------------------------------------------------------
extern "C" void kernel_launch(void* const* d_in, const int* in_sizes, int n_in,
                              void* d_out, int out_size, void* d_ws, size_t ws_size,
                              hipStream_t stream)
{
    const float* x      = (const float*)d_in[0];
    const float* coords = (const float*)d_in[1];
    const int*   nidx   = (const int*)d_in[2];
    const float* W_top  = (const float*)d_in[3];
    const float* b_top  = (const float*)d_in[4];
    const float* W_down = (const float*)d_in[5];
    const float* b_down = (const float*)d_in[6];
    const float* W_phi  = (const float*)d_in[7];
    const float* b_phi  = (const float*)d_in[8];
    const float* W_psi  = (const float*)d_in[9];
    const float* b_psi  = (const float*)d_in[10];
    const float* W_alpha= (const float*)d_in[11];
    const float* b_alpha= (const float*)d_in[12];
    const float* W_d1   = (const float*)d_in[13];
    const float* b_d1   = (const float*)d_in[14];
    const float* W_d2   = (const float*)d_in[15];
    const float* b_d2   = (const float*)d_in[16];
    const float* W_g1   = (const float*)d_in[17];
    const float* b_g1   = (const float*)d_in[18];
    const float* W_g2   = (const float*)d_in[19];
    const float* b_g2   = (const float*)d_in[20];
    (void)b_g2; // softmax shift-invariant

    const int N = in_sizes[0] / C;

    ushort_t* WTt  = (ushort_t*)d_ws;
    ushort_t* WTp  = WTt  + C*C;
    ushort_t* WTs  = WTp  + C*C;
    ushort_t* WTa  = WTs  + C*C;
    ushort_t* WTd2 = WTa  + C*C;
    ushort_t* WTg1 = WTd2 + C*C;
    ushort_t* WTg2 = WTg1 + C*C;
    ushort_t* WTdn = WTg2 + C*C;
    ushort_t* phiB = WTdn + C*C;
    ushort_t* psiB = phiB + (size_t)N*C;
    ushort_t* alfB = psiB + (size_t)N*C;
    float* out = (float*)d_out;

    hipLaunchKernelGGL(k_prep, dim3(4*C), dim3(C), 0, stream,
        W_top, W_phi, W_psi, W_alpha, WTt, WTp, WTs, WTa);
    hipLaunchKernelGGL(k_prep, dim3(4*C), dim3(C), 0, stream,
        W_d2, W_g1, W_g2, W_down, WTd2, WTg1, WTg2, WTdn);

    hipLaunchKernelGGL(k_qkv2, dim3(N / 64), dim3(512), 0, stream,
        x, WTt, b_top, WTp, b_phi, WTs, b_psi, WTa, b_alpha,
        phiB, psiB, alfB);

    const int npairs = N / 2;
    const int NBLK = 4096;
    const int ppb = (npairs + NBLK - 1) / NBLK;
    hipLaunchKernelGGL(k_attn3, dim3(NBLK), dim3(512), 0, stream,
        phiB, psiB, alfB, coords, nidx,
        W_d1, b_d1, WTd2, b_d2, WTg1, b_g1, WTg2,
        WTdn, b_down, x, out, npairs, ppb);
}

// Round 5
// 683.529 us; speedup vs baseline: 1.5317x; 1.0682x over previous
//
#include <hip/hip_runtime.h>
#include <math.h>

#define C 128
#define K 16
#define M 4              // points per group
#define ROWS 64          // M*K rows per tile

typedef unsigned short ushort_t;
typedef unsigned int u32;
typedef float f32x4 __attribute__((ext_vector_type(4)));
typedef _Float16 f16x8 __attribute__((ext_vector_type(8)));

union U8h { _Float16 h[8]; uint4 u; };

__device__ __forceinline__ float f16tof(ushort_t b) {
    _Float16 h = __builtin_bit_cast(_Float16, b); return (float)h;
}
__device__ __forceinline__ ushort_t ftof16(float f) {
    _Float16 h = (_Float16)f; return __builtin_bit_cast(ushort_t, h);
}
__device__ __forceinline__ f32x4 mfma16(f16x8 a, f16x8 b, f32x4 c) {
    return __builtin_amdgcn_mfma_f32_16x16x32_f16(a, b, c, 0, 0, 0);
}

// ---------------------------------------------------------------------------
// Prep: transpose+convert 4 weight matrices fp32 -> fp16, WT[n][e] layout.
// ---------------------------------------------------------------------------
__global__ __launch_bounds__(128) void k_prep(
    const float* __restrict__ s0, const float* __restrict__ s1,
    const float* __restrict__ s2, const float* __restrict__ s3,
    ushort_t* __restrict__ d0, ushort_t* __restrict__ d1,
    ushort_t* __restrict__ d2, ushort_t* __restrict__ d3)
{
    const int m = blockIdx.x >> 7, n = blockIdx.x & 127, e = threadIdx.x;
    const float* s = (m==0) ? s0 : (m==1) ? s1 : (m==2) ? s2 : s3;
    ushort_t*   d = (m==0) ? d0 : (m==1) ? d1 : (m==2) ? d2 : d3;
    d[n*C + e] = ftof16(s[e*C + n]);
}

// ---------------------------------------------------------------------------
// Kernel 1: h = x@W_top + b; phi/psi/alpha = h@W_* + b   via f16 MFMA.
// (unchanged from R2/R4 — correct and fast enough for now)
// ---------------------------------------------------------------------------
__global__ __launch_bounds__(512) void k_qkv2(
    const float* __restrict__ x,
    const ushort_t* __restrict__ WTt, const float* __restrict__ bt,
    const ushort_t* __restrict__ WTp, const float* __restrict__ bp,
    const ushort_t* __restrict__ WTs, const float* __restrict__ bs,
    const ushort_t* __restrict__ WTa, const float* __restrict__ ba,
    ushort_t* __restrict__ phiB, ushort_t* __restrict__ psiB,
    ushort_t* __restrict__ alfB)
{
    __shared__ ushort_t sX[64*C];
    __shared__ ushort_t sH[64*C];
    const int tid = threadIdx.x, lane = tid & 63, wv = tid >> 6;
    const int ncol = (wv<<4) + (lane&15), arow = lane&15;
    const int kgrp = lane>>4, krow0 = kgrp<<3;
    const int r0 = blockIdx.x * 64;

    {
        const int rX = tid>>3, cX = (tid&7)<<4;
        const float* xp = &x[(size_t)(r0+rX)*C + cX];
        #pragma unroll
        for (int hf = 0; hf < 2; ++hf) {
            const float4 a  = *(const float4*)&xp[hf*8 + 0];
            const float4 b2 = *(const float4*)&xp[hf*8 + 4];
            U8h v;
            v.h[0]=(_Float16)a.x;  v.h[1]=(_Float16)a.y;
            v.h[2]=(_Float16)a.z;  v.h[3]=(_Float16)a.w;
            v.h[4]=(_Float16)b2.x; v.h[5]=(_Float16)b2.y;
            v.h[6]=(_Float16)b2.z; v.h[7]=(_Float16)b2.w;
            const int col = cX + hf*8;
            *(uint4*)&sX[(rX<<7) + (col ^ ((rX&7)<<3))] = v.u;
        }
    }
    __syncthreads();

    {
        f16x8 bf[4]; f32x4 hacc[4];
        #pragma unroll
        for (int kk = 0; kk < 4; ++kk)
            bf[kk] = *(const f16x8*)&WTt[(size_t)ncol*C + (kk<<5) + krow0];
        #pragma unroll
        for (int m = 0; m < 4; ++m) hacc[m] = (f32x4){0.f,0.f,0.f,0.f};
        __builtin_amdgcn_s_setprio(1);
        #pragma unroll
        for (int m = 0; m < 4; ++m)
            #pragma unroll
            for (int kk = 0; kk < 4; ++kk) {
                const int row = (m<<4) + arow;
                const f16x8 af = *(const f16x8*)&sX[(row<<7) + (((kk<<5)+krow0) ^ ((arow&7)<<3))];
                hacc[m] = mfma16(af, bf[kk], hacc[m]);
            }
        __builtin_amdgcn_s_setprio(0);
        const float btc = bt[ncol];
        #pragma unroll
        for (int m = 0; m < 4; ++m)
            #pragma unroll
            for (int r = 0; r < 4; ++r) {
                const int row = (m<<4) + (kgrp<<2) + r;
                const u32 hv = ftof16(hacc[m][r] + btc);
                const u32 pv = (u32)__shfl_xor((int)hv, 1);
                if (!(lane&1))
                    *(u32*)&sH[(row<<7) + (ncol ^ ((row&7)<<3))] = hv | (pv<<16);
            }
    }
    __syncthreads();

#define OGEMM(WT_, b_, o_)                                                    \
    {                                                                         \
        f16x8 wf[4]; f32x4 oacc[4];                                           \
        _Pragma("unroll")                                                     \
        for (int kk = 0; kk < 4; ++kk)                                        \
            wf[kk] = *(const f16x8*)&WT_[(size_t)ncol*C + (kk<<5) + krow0];   \
        _Pragma("unroll")                                                     \
        for (int m = 0; m < 4; ++m) oacc[m] = (f32x4){0.f,0.f,0.f,0.f};      \
        __builtin_amdgcn_s_setprio(1);                                        \
        _Pragma("unroll")                                                     \
        for (int m = 0; m < 4; ++m)                                           \
            _Pragma("unroll")                                                 \
            for (int kk = 0; kk < 4; ++kk) {                                  \
                const int row = (m<<4) + arow;                                \
                const f16x8 af = *(const f16x8*)&sH[(row<<7) + (((kk<<5)+krow0) ^ ((arow&7)<<3))]; \
                oacc[m] = mfma16(af, wf[kk], oacc[m]);                        \
            }                                                                 \
        __builtin_amdgcn_s_setprio(0);                                        \
        const float bc = b_[ncol];                                            \
        _Pragma("unroll")                                                     \
        for (int m = 0; m < 4; ++m)                                           \
            _Pragma("unroll")                                                 \
            for (int r = 0; r < 4; ++r) {                                     \
                const int row = (m<<4) + (kgrp<<2) + r;                       \
                const u32 hv = ftof16(oacc[m][r] + bc);                       \
                const u32 pv = (u32)__shfl_xor((int)hv, 1);                   \
                if (!(lane&1))                                                \
                    *(u32*)&o_[(size_t)(r0+row)*C + ncol] = hv | (pv<<16);    \
            }                                                                 \
    }
    OGEMM(WTp, bp, phiB)
    OGEMM(WTs, bs, psiB)
    OGEMM(WTa, ba, alfB)
#undef OGEMM
}

// ---------------------------------------------------------------------------
// Kernel 2: fused vector attention, 4 points (64 rows) per group.
// 512 thr / 8 waves; wave owns cols [16w,16w+16); m-tile m == point m.
// LDS: sT0/sT1 = t1 hi/lo (sT0 -> u, sT1 -> alpha in phase 3);
//      sA0/sA1 = attn hi/lo (sA0 starts as base = phi - psi).
// 4 barriers per group; 2 blocks/CU resident (68 KB LDS, VGPR<=128).
// ---------------------------------------------------------------------------
__global__ __launch_bounds__(512, 2) void k_attn4(
    const ushort_t* __restrict__ phiB, const ushort_t* __restrict__ psiB,
    const ushort_t* __restrict__ alfB,
    const float* __restrict__ coords, const int* __restrict__ nidx,
    const float* __restrict__ Wd1, const float* __restrict__ bd1,
    const ushort_t* __restrict__ WTd2, const float* __restrict__ bd2,
    const ushort_t* __restrict__ WTg1, const float* __restrict__ bg1,
    const ushort_t* __restrict__ WTg2,
    const ushort_t* __restrict__ WTdn, const float* __restrict__ bdn,
    const float* __restrict__ x, float* __restrict__ out,
    int ngroups, int gpb)
{
    __shared__ ushort_t sT0[ROWS*C], sT1[ROWS*C];   // t1 hi/lo -> u / alpha
    __shared__ ushort_t sA0[ROWS*C], sA1[ROWS*C];   // base/attn hi, attn lo
    __shared__ float    sWd1[3][C];
    __shared__ float    sbd1v[C];
    __shared__ float    sY[M][C];

    const int tid  = threadIdx.x, lane = tid & 63, wv = tid >> 6;
    const int ncol = (wv<<4) + (lane&15);
    const int arow = lane & 15;
    const int kgrp = lane >> 4, krow0 = kgrp << 3;
    const int grow = tid >> 3;            // gather row 0..63
    const int gpt  = grow >> 4;           // point-in-group 0..3
    const int gk   = grow & 15;           // neighbor index 0..15
    const int gc   = (tid & 7) << 4;      // 16-ch slice base

    const int g0 = blockIdx.x * gpb;
    if (g0 >= ngroups) return;
    const int gend = (g0 + gpb < ngroups) ? (g0 + gpb) : ngroups;

    if (tid < 3*C) ((float*)sWd1)[tid] = Wd1[tid];
    else if (tid < 4*C) sbd1v[tid - 3*C] = bd1[tid - 3*C];

    // persistent weight fragments (64 VGPR)
    f16x8 wd2[4], wg1[4], wg2[4], wdn[4];
    #pragma unroll
    for (int kk = 0; kk < 4; ++kk) {
        wd2[kk] = *(const f16x8*)&WTd2[(size_t)ncol*C + (kk<<5) + krow0];
        wg1[kk] = *(const f16x8*)&WTg1[(size_t)ncol*C + (kk<<5) + krow0];
        wg2[kk] = *(const f16x8*)&WTg2[(size_t)ncol*C + (kk<<5) + krow0];
        wdn[kk] = *(const f16x8*)&WTdn[(size_t)ncol*C + (kgrp<<5) + (kk<<3)];
    }
    const float bd2c = bd2[ncol], bg1c = bg1[ncol], bdnc = bdn[ncol];

    __syncthreads();   // sWd1 staged

    // prologue prefetch: this thread's gather row for group g0
    int jP; float cn0,cn1,cn2,cj0,cj1,cj2;
    {
        const int pt = g0*M + gpt;
        jP  = nidx[(size_t)pt*K + gk];
        cn0 = coords[(size_t)pt*3+0]; cn1 = coords[(size_t)pt*3+1]; cn2 = coords[(size_t)pt*3+2];
        cj0 = coords[(size_t)jP*3+0]; cj1 = coords[(size_t)jP*3+1]; cj2 = coords[(size_t)jP*3+2];
    }

    const int si0 = (grow<<7) + (gc ^ ((grow&7)<<3));
    const int si1 = (grow<<7) + ((gc+8) ^ ((grow&7)<<3));

    for (int g = g0; g < gend; ++g) {
        const int p0 = g * M;
        const bool hn = (g + 1 < gend);

        // ======== phase 1: gathers, t1 (hi/lo), base = phi - psi ========
        const size_t jrow = (size_t)jP * C;
        const uint4 psi0 = *(const uint4*)&psiB[jrow + gc];
        const uint4 psi1 = *(const uint4*)&psiB[jrow + gc + 8];
        const uint4 alf0 = *(const uint4*)&alfB[jrow + gc];     // held to ph.3
        const uint4 alf1 = *(const uint4*)&alfB[jrow + gc + 8];
        const size_t prow = (size_t)(p0 + gpt) * C;
        const uint4 phi0 = *(const uint4*)&phiB[prow + gc];
        const uint4 phi1 = *(const uint4*)&phiB[prow + gc + 8];

        const float rx = cn0 - cj0, ry = cn1 - cj1, rz = cn2 - cj2;
        #pragma unroll
        for (int hf = 0; hf < 2; ++hf) {
            U8h hi, lo;
            #pragma unroll
            for (int z = 0; z < 8; ++z) {
                const int c = gc + (hf<<3) + z;
                float t = fmaf(rx, sWd1[0][c],
                          fmaf(ry, sWd1[1][c],
                          fmaf(rz, sWd1[2][c], sbd1v[c])));
                t = fmaxf(t, 0.f);
                hi.h[z] = (_Float16)t;
                lo.h[z] = (_Float16)(t - (float)hi.h[z]);
            }
            const int si = hf ? si1 : si0;
            *(uint4*)&sT0[si] = hi.u;
            *(uint4*)&sT1[si] = lo.u;
        }
        {
            U8h P, S, B;
            P.u = phi0; S.u = psi0;
            #pragma unroll
            for (int z = 0; z < 8; ++z) B.h[z] = P.h[z] - S.h[z];
            *(uint4*)&sA0[si0] = B.u;
            P.u = phi1; S.u = psi1;
            #pragma unroll
            for (int z = 0; z < 8; ++z) B.h[z] = P.h[z] - S.h[z];
            *(uint4*)&sA0[si1] = B.u;
        }
        __syncthreads();                                        // S1

        // ======== phase 2: pos = t1 @ Wd2 + bd2 ; attn RMW into sA ========
        f32x4 pos[M];
        #pragma unroll
        for (int m = 0; m < M; ++m) pos[m] = (f32x4){0.f,0.f,0.f,0.f};
        __builtin_amdgcn_s_setprio(1);
        #pragma unroll
        for (int m = 0; m < M; ++m)
            #pragma unroll
            for (int kk = 0; kk < 4; ++kk) {
                const int si = (((m<<4)+arow)<<7) + (((kk<<5)+krow0) ^ ((arow&7)<<3));
                pos[m] = mfma16(*(const f16x8*)&sT0[si], wd2[kk], pos[m]);
                pos[m] = mfma16(*(const f16x8*)&sT1[si], wd2[kk], pos[m]);
            }
        __builtin_amdgcn_s_setprio(0);
        #pragma unroll
        for (int m = 0; m < M; ++m)
            #pragma unroll
            for (int z = 0; z < 4; ++z) pos[m][z] += bd2c;

        #pragma unroll
        for (int m = 0; m < M; ++m)
            #pragma unroll
            for (int r = 0; r < 4; ++r) {
                const int row = (m<<4) + (kgrp<<2) + r;
                const int si  = (row<<7) + (ncol ^ ((row&7)<<3));
                const float av = f16tof(sA0[si]) + pos[m][r];
                const _Float16 h = (_Float16)av;
                const u32 hv = __builtin_bit_cast(ushort_t, h);
                const u32 lv = ftof16(av - (float)h);
                const u32 hp = (u32)__shfl_xor((int)hv, 1);
                const u32 lp = (u32)__shfl_xor((int)lv, 1);
                if (!(lane&1)) {
                    *(u32*)&sA0[si] = hv | (hp<<16);
                    *(u32*)&sA1[si] = lv | (lp<<16);
                }
            }
        __syncthreads();                                        // S2

        // ======== phase 3: u = relu(attn@Wg1+bg1) -> sT0; alpha -> sT1 ====
        *(uint4*)&sT1[si0] = alf0;
        *(uint4*)&sT1[si1] = alf1;
        {
            f32x4 ua[M];
            #pragma unroll
            for (int m = 0; m < M; ++m) ua[m] = (f32x4){0.f,0.f,0.f,0.f};
            __builtin_amdgcn_s_setprio(1);
            #pragma unroll
            for (int m = 0; m < M; ++m)
                #pragma unroll
                for (int kk = 0; kk < 4; ++kk) {
                    const int si = (((m<<4)+arow)<<7) + (((kk<<5)+krow0) ^ ((arow&7)<<3));
                    ua[m] = mfma16(*(const f16x8*)&sA0[si], wg1[kk], ua[m]);
                    ua[m] = mfma16(*(const f16x8*)&sA1[si], wg1[kk], ua[m]);
                }
            __builtin_amdgcn_s_setprio(0);
            #pragma unroll
            for (int m = 0; m < M; ++m)
                #pragma unroll
                for (int r = 0; r < 4; ++r) {
                    const int row = (m<<4) + (kgrp<<2) + r;
                    const int si  = (row<<7) + (ncol ^ ((row&7)<<3));
                    const u32 hv = ftof16(fmaxf(ua[m][r] + bg1c, 0.f));
                    const u32 hp = (u32)__shfl_xor((int)hv, 1);
                    if (!(lane&1)) *(u32*)&sT0[si] = hv | (hp<<16);
                }
        }
        // prefetch next group's neighbor idx + coords
        if (hn) {
            const int pt = (g+1)*M + gpt;
            jP  = nidx[(size_t)pt*K + gk];
            cn0 = coords[(size_t)pt*3+0]; cn1 = coords[(size_t)pt*3+1]; cn2 = coords[(size_t)pt*3+2];
            cj0 = coords[(size_t)jP*3+0]; cj1 = coords[(size_t)jP*3+1]; cj2 = coords[(size_t)jP*3+2];
        }
        __syncthreads();                                        // S3

        // ======== phase 4: logits = u@Wg2 ; softmax ; y -> sY ========
        f32x4 lg[M];
        #pragma unroll
        for (int m = 0; m < M; ++m) lg[m] = (f32x4){0.f,0.f,0.f,0.f};
        __builtin_amdgcn_s_setprio(1);
        #pragma unroll
        for (int m = 0; m < M; ++m)
            #pragma unroll
            for (int kk = 0; kk < 4; ++kk) {
                const int si = (((m<<4)+arow)<<7) + (((kk<<5)+krow0) ^ ((arow&7)<<3));
                lg[m] = mfma16(*(const f16x8*)&sT0[si], wg2[kk], lg[m]);
            }
        __builtin_amdgcn_s_setprio(0);

        #pragma unroll
        for (int m = 0; m < M; ++m) {
            float mx = fmaxf(fmaxf(lg[m][0], lg[m][1]), fmaxf(lg[m][2], lg[m][3]));
            mx = fmaxf(mx, __shfl_xor(mx, 16));
            mx = fmaxf(mx, __shfl_xor(mx, 32));
            const float e0 = __expf(lg[m][0]-mx), e1 = __expf(lg[m][1]-mx);
            const float e2 = __expf(lg[m][2]-mx), e3 = __expf(lg[m][3]-mx);
            float den = e0 + e1 + e2 + e3;
            den += __shfl_xor(den, 16);
            den += __shfl_xor(den, 32);
            const float inv = 1.0f / den;
            const int rr0 = (m<<4) + (kgrp<<2);
            float yp;
            yp  = e0 * (f16tof(sT1[((rr0+0)<<7) + (ncol ^ (((rr0+0)&7)<<3))]) + pos[m][0]);
            yp += e1 * (f16tof(sT1[((rr0+1)<<7) + (ncol ^ (((rr0+1)&7)<<3))]) + pos[m][1]);
            yp += e2 * (f16tof(sT1[((rr0+2)<<7) + (ncol ^ (((rr0+2)&7)<<3))]) + pos[m][2]);
            yp += e3 * (f16tof(sT1[((rr0+3)<<7) + (ncol ^ (((rr0+3)&7)<<3))]) + pos[m][3]);
            yp *= inv;
            yp += __shfl_xor(yp, 16);
            yp += __shfl_xor(yp, 32);
            if (lane < 16) sY[m][ncol] = yp;
        }
        __syncthreads();                                        // S4

        // ======== phase 5: out = y @ W_down + b_down + x ========
        #pragma unroll
        for (int m = 0; m < M; ++m) {
            float acc = 0.f;
            const int e0i = kgrp << 5;
            #pragma unroll
            for (int z = 0; z < 4; ++z) {
                const float4 ya = *(const float4*)&sY[m][e0i + (z<<3)];
                const float4 yb = *(const float4*)&sY[m][e0i + (z<<3) + 4];
                const f16x8 w8 = wdn[z];
                acc = fmaf(ya.x, (float)w8[0], acc);
                acc = fmaf(ya.y, (float)w8[1], acc);
                acc = fmaf(ya.z, (float)w8[2], acc);
                acc = fmaf(ya.w, (float)w8[3], acc);
                acc = fmaf(yb.x, (float)w8[4], acc);
                acc = fmaf(yb.y, (float)w8[5], acc);
                acc = fmaf(yb.z, (float)w8[6], acc);
                acc = fmaf(yb.w, (float)w8[7], acc);
            }
            acc += __shfl_xor(acc, 16);
            acc += __shfl_xor(acc, 32);
            if (lane < 16) {
                const size_t p = (size_t)(p0 + m);
                out[p*C + ncol] = acc + bdnc + x[p*C + ncol];
            }
        }
    }
}

// ---------------------------------------------------------------------------
extern "C" void kernel_launch(void* const* d_in, const int* in_sizes, int n_in,
                              void* d_out, int out_size, void* d_ws, size_t ws_size,
                              hipStream_t stream)
{
    const float* x      = (const float*)d_in[0];
    const float* coords = (const float*)d_in[1];
    const int*   nidx   = (const int*)d_in[2];
    const float* W_top  = (const float*)d_in[3];
    const float* b_top  = (const float*)d_in[4];
    const float* W_down = (const float*)d_in[5];
    const float* b_down = (const float*)d_in[6];
    const float* W_phi  = (const float*)d_in[7];
    const float* b_phi  = (const float*)d_in[8];
    const float* W_psi  = (const float*)d_in[9];
    const float* b_psi  = (const float*)d_in[10];
    const float* W_alpha= (const float*)d_in[11];
    const float* b_alpha= (const float*)d_in[12];
    const float* W_d1   = (const float*)d_in[13];
    const float* b_d1   = (const float*)d_in[14];
    const float* W_d2   = (const float*)d_in[15];
    const float* b_d2   = (const float*)d_in[16];
    const float* W_g1   = (const float*)d_in[17];
    const float* b_g1   = (const float*)d_in[18];
    const float* W_g2   = (const float*)d_in[19];
    const float* b_g2   = (const float*)d_in[20];
    (void)b_g2; // softmax shift-invariant

    const int N = in_sizes[0] / C;

    ushort_t* WTt  = (ushort_t*)d_ws;
    ushort_t* WTp  = WTt  + C*C;
    ushort_t* WTs  = WTp  + C*C;
    ushort_t* WTa  = WTs  + C*C;
    ushort_t* WTd2 = WTa  + C*C;
    ushort_t* WTg1 = WTd2 + C*C;
    ushort_t* WTg2 = WTg1 + C*C;
    ushort_t* WTdn = WTg2 + C*C;
    ushort_t* phiB = WTdn + C*C;
    ushort_t* psiB = phiB + (size_t)N*C;
    ushort_t* alfB = psiB + (size_t)N*C;
    float* out = (float*)d_out;

    hipLaunchKernelGGL(k_prep, dim3(4*C), dim3(C), 0, stream,
        W_top, W_phi, W_psi, W_alpha, WTt, WTp, WTs, WTa);
    hipLaunchKernelGGL(k_prep, dim3(4*C), dim3(C), 0, stream,
        W_d2, W_g1, W_g2, W_down, WTd2, WTg1, WTg2, WTdn);

    hipLaunchKernelGGL(k_qkv2, dim3(N / 64), dim3(512), 0, stream,
        x, WTt, b_top, WTp, b_phi, WTs, b_psi, WTa, b_alpha,
        phiB, psiB, alfB);

    const int ngroups = N / M;                 // 16384
    const int NBLK = 2048;
    const int gpb = (ngroups + NBLK - 1) / NBLK;
    hipLaunchKernelGGL(k_attn4, dim3(NBLK), dim3(512), 0, stream,
        phiB, psiB, alfB, coords, nidx,
        W_d1, b_d1, WTd2, b_d2, WTg1, b_g1, WTg2,
        WTdn, b_down, x, out, ngroups, gpb);
}

// Round 6
// 634.367 us; speedup vs baseline: 1.6504x; 1.0775x over previous
//
#include <hip/hip_runtime.h>
#include <math.h>

#define C 128
#define K 16
#define M 4              // points per group
#define ROWS 64          // M*K rows per tile

typedef unsigned short ushort_t;
typedef unsigned int u32;
typedef float f32x4 __attribute__((ext_vector_type(4)));
typedef _Float16 f16x8 __attribute__((ext_vector_type(8)));

union U8h { _Float16 h[8]; uint4 u; };

__device__ __forceinline__ float f16tof(ushort_t b) {
    _Float16 h = __builtin_bit_cast(_Float16, b); return (float)h;
}
__device__ __forceinline__ ushort_t ftof16(float f) {
    _Float16 h = (_Float16)f; return __builtin_bit_cast(ushort_t, h);
}
__device__ __forceinline__ f32x4 mfma16(f16x8 a, f16x8 b, f32x4 c) {
    return __builtin_amdgcn_mfma_f32_16x16x32_f16(a, b, c, 0, 0, 0);
}

// ---------------------------------------------------------------------------
// Prep: transpose+convert 4 weight matrices fp32 -> fp16, WT[n][e] layout.
// ---------------------------------------------------------------------------
__global__ __launch_bounds__(128) void k_prep(
    const float* __restrict__ s0, const float* __restrict__ s1,
    const float* __restrict__ s2, const float* __restrict__ s3,
    ushort_t* __restrict__ d0, ushort_t* __restrict__ d1,
    ushort_t* __restrict__ d2, ushort_t* __restrict__ d3)
{
    const int m = blockIdx.x >> 7, n = blockIdx.x & 127, e = threadIdx.x;
    const float* s = (m==0) ? s0 : (m==1) ? s1 : (m==2) ? s2 : s3;
    ushort_t*   d = (m==0) ? d0 : (m==1) ? d1 : (m==2) ? d2 : d3;
    d[n*C + e] = ftof16(s[e*C + n]);
}

// ---------------------------------------------------------------------------
// Kernel 1: h = x@W_top + b; phi/psi/alpha = h@W_* + b   via f16 MFMA.
// ---------------------------------------------------------------------------
__global__ __launch_bounds__(512) void k_qkv2(
    const float* __restrict__ x,
    const ushort_t* __restrict__ WTt, const float* __restrict__ bt,
    const ushort_t* __restrict__ WTp, const float* __restrict__ bp,
    const ushort_t* __restrict__ WTs, const float* __restrict__ bs,
    const ushort_t* __restrict__ WTa, const float* __restrict__ ba,
    ushort_t* __restrict__ phiB, ushort_t* __restrict__ psiB,
    ushort_t* __restrict__ alfB)
{
    __shared__ ushort_t sX[64*C];
    __shared__ ushort_t sH[64*C];
    const int tid = threadIdx.x, lane = tid & 63, wv = tid >> 6;
    const int ncol = (wv<<4) + (lane&15), arow = lane&15;
    const int kgrp = lane>>4, krow0 = kgrp<<3;
    const int r0 = blockIdx.x * 64;

    {
        const int rX = tid>>3, cX = (tid&7)<<4;
        const float* xp = &x[(size_t)(r0+rX)*C + cX];
        #pragma unroll
        for (int hf = 0; hf < 2; ++hf) {
            const float4 a  = *(const float4*)&xp[hf*8 + 0];
            const float4 b2 = *(const float4*)&xp[hf*8 + 4];
            U8h v;
            v.h[0]=(_Float16)a.x;  v.h[1]=(_Float16)a.y;
            v.h[2]=(_Float16)a.z;  v.h[3]=(_Float16)a.w;
            v.h[4]=(_Float16)b2.x; v.h[5]=(_Float16)b2.y;
            v.h[6]=(_Float16)b2.z; v.h[7]=(_Float16)b2.w;
            const int col = cX + hf*8;
            *(uint4*)&sX[(rX<<7) + (col ^ ((rX&7)<<3))] = v.u;
        }
    }
    __syncthreads();

    {
        f16x8 bf[4]; f32x4 hacc[4];
        #pragma unroll
        for (int kk = 0; kk < 4; ++kk)
            bf[kk] = *(const f16x8*)&WTt[(size_t)ncol*C + (kk<<5) + krow0];
        #pragma unroll
        for (int m = 0; m < 4; ++m) hacc[m] = (f32x4){0.f,0.f,0.f,0.f};
        __builtin_amdgcn_s_setprio(1);
        #pragma unroll
        for (int m = 0; m < 4; ++m)
            #pragma unroll
            for (int kk = 0; kk < 4; ++kk) {
                const int row = (m<<4) + arow;
                const f16x8 af = *(const f16x8*)&sX[(row<<7) + (((kk<<5)+krow0) ^ ((arow&7)<<3))];
                hacc[m] = mfma16(af, bf[kk], hacc[m]);
            }
        __builtin_amdgcn_s_setprio(0);
        const float btc = bt[ncol];
        #pragma unroll
        for (int m = 0; m < 4; ++m)
            #pragma unroll
            for (int r = 0; r < 4; ++r) {
                const int row = (m<<4) + (kgrp<<2) + r;
                const u32 hv = ftof16(hacc[m][r] + btc);
                const u32 pv = (u32)__shfl_xor((int)hv, 1);
                if (!(lane&1))
                    *(u32*)&sH[(row<<7) + (ncol ^ ((row&7)<<3))] = hv | (pv<<16);
            }
    }
    __syncthreads();

#define OGEMM(WT_, b_, o_)                                                    \
    {                                                                         \
        f16x8 wf[4]; f32x4 oacc[4];                                           \
        _Pragma("unroll")                                                     \
        for (int kk = 0; kk < 4; ++kk)                                        \
            wf[kk] = *(const f16x8*)&WT_[(size_t)ncol*C + (kk<<5) + krow0];   \
        _Pragma("unroll")                                                     \
        for (int m = 0; m < 4; ++m) oacc[m] = (f32x4){0.f,0.f,0.f,0.f};      \
        __builtin_amdgcn_s_setprio(1);                                        \
        _Pragma("unroll")                                                     \
        for (int m = 0; m < 4; ++m)                                           \
            _Pragma("unroll")                                                 \
            for (int kk = 0; kk < 4; ++kk) {                                  \
                const int row = (m<<4) + arow;                                \
                const f16x8 af = *(const f16x8*)&sH[(row<<7) + (((kk<<5)+krow0) ^ ((arow&7)<<3))]; \
                oacc[m] = mfma16(af, wf[kk], oacc[m]);                        \
            }                                                                 \
        __builtin_amdgcn_s_setprio(0);                                        \
        const float bc = b_[ncol];                                            \
        _Pragma("unroll")                                                     \
        for (int m = 0; m < 4; ++m)                                           \
            _Pragma("unroll")                                                 \
            for (int r = 0; r < 4; ++r) {                                     \
                const int row = (m<<4) + (kgrp<<2) + r;                       \
                const u32 hv = ftof16(oacc[m][r] + bc);                       \
                const u32 pv = (u32)__shfl_xor((int)hv, 1);                   \
                if (!(lane&1))                                                \
                    *(u32*)&o_[(size_t)(r0+row)*C + ncol] = hv | (pv<<16);    \
            }                                                                 \
    }
    OGEMM(WTp, bp, phiB)
    OGEMM(WTs, bs, psiB)
    OGEMM(WTa, ba, alfB)
#undef OGEMM
}

// ---------------------------------------------------------------------------
// Kernel 2: fused vector attention, 4 points (64 rows) per group.
// t1 kept hi/lo f16 (large amplitude); attn/u single f16.
// psi/phi/alpha/nidx consumed DIRECTLY from global at C-layout positions
// (L1-hot; no LDS staging, no scalar LDS reads).
// LDS: sT0 (t1 hi), sT1 (t1 lo -> u), sA (attn), sY, sWd1. ~50 KB.
// ---------------------------------------------------------------------------
__global__ __launch_bounds__(512, 2) void k_attn5(
    const ushort_t* __restrict__ phiB, const ushort_t* __restrict__ psiB,
    const ushort_t* __restrict__ alfB,
    const float* __restrict__ coords, const int* __restrict__ nidx,
    const float* __restrict__ Wd1, const float* __restrict__ bd1,
    const ushort_t* __restrict__ WTd2, const float* __restrict__ bd2,
    const ushort_t* __restrict__ WTg1, const float* __restrict__ bg1,
    const ushort_t* __restrict__ WTg2,
    const ushort_t* __restrict__ WTdn, const float* __restrict__ bdn,
    const float* __restrict__ x, float* __restrict__ out,
    int ngroups, int gpb)
{
    __shared__ ushort_t sT0[ROWS*C];   // t1 hi
    __shared__ ushort_t sT1[ROWS*C];   // t1 lo, then u
    __shared__ ushort_t sA[ROWS*C];    // attn (single f16)
    __shared__ float    sWd1[3][C];
    __shared__ float    sbd1v[C];
    __shared__ float    sY[M][C];

    const int tid  = threadIdx.x, lane = tid & 63, wv = tid >> 6;
    const int ncol = (wv<<4) + (lane&15);
    const int arow = lane & 15;
    const int kgrp = lane >> 4, krow0 = kgrp << 3;
    const int grow = tid >> 3;            // t1 row 0..63
    const int gpt  = grow >> 4;           // point-in-group 0..3
    const int gk   = grow & 15;           // neighbor 0..15
    const int gc   = (tid & 7) << 4;      // 16-ch slice base

    const int g0 = blockIdx.x * gpb;
    if (g0 >= ngroups) return;
    const int gend = (g0 + gpb < ngroups) ? (g0 + gpb) : ngroups;

    if (tid < 3*C) ((float*)sWd1)[tid] = Wd1[tid];
    else if (tid < 4*C) sbd1v[tid - 3*C] = bd1[tid - 3*C];

    // persistent weight fragments (64 VGPR)
    f16x8 wd2[4], wg1[4], wg2[4], wdn[4];
    #pragma unroll
    for (int kk = 0; kk < 4; ++kk) {
        wd2[kk] = *(const f16x8*)&WTd2[(size_t)ncol*C + (kk<<5) + krow0];
        wg1[kk] = *(const f16x8*)&WTg1[(size_t)ncol*C + (kk<<5) + krow0];
        wg2[kk] = *(const f16x8*)&WTg2[(size_t)ncol*C + (kk<<5) + krow0];
        wdn[kk] = *(const f16x8*)&WTdn[(size_t)ncol*C + (kgrp<<5) + (kk<<3)];
    }
    const float bd2c = bd2[ncol], bg1c = bg1[ncol], bdnc = bdn[ncol];

    __syncthreads();   // sWd1 staged

    // prologue prefetch (t1 inputs for group g0, grow layout)
    int jP; float cn0,cn1,cn2,cj0,cj1,cj2;
    {
        const int pt = g0*M + gpt;
        jP  = nidx[(size_t)pt*K + gk];
        cn0 = coords[(size_t)pt*3+0]; cn1 = coords[(size_t)pt*3+1]; cn2 = coords[(size_t)pt*3+2];
        cj0 = coords[(size_t)jP*3+0]; cj1 = coords[(size_t)jP*3+1]; cj2 = coords[(size_t)jP*3+2];
    }

    const int si0 = (grow<<7) + (gc ^ ((grow&7)<<3));
    const int si1 = (grow<<7) + ((gc+8) ^ ((grow&7)<<3));

    for (int g = g0; g < gend; ++g) {
        const int p0 = g * M;
        const bool hn = (g + 1 < gend);

        // ======== phase 1: t1 = relu(rel@Wd1+bd1), hi/lo -> sT0/sT1 ========
        {
            const float rx = cn0 - cj0, ry = cn1 - cj1, rz = cn2 - cj2;
            #pragma unroll
            for (int hf = 0; hf < 2; ++hf) {
                U8h hi, lo;
                #pragma unroll
                for (int z = 0; z < 8; ++z) {
                    const int c = gc + (hf<<3) + z;
                    float t = fmaf(rx, sWd1[0][c],
                              fmaf(ry, sWd1[1][c],
                              fmaf(rz, sWd1[2][c], sbd1v[c])));
                    t = fmaxf(t, 0.f);
                    hi.h[z] = (_Float16)t;
                    lo.h[z] = (_Float16)(t - (float)hi.h[z]);
                }
                const int si = hf ? si1 : si0;
                *(uint4*)&sT0[si] = hi.u;
                *(uint4*)&sT1[si] = lo.u;
            }
        }
        __syncthreads();                                        // S1

        // ======== phase 2: issue psi/phi loads; pos MFMA; attn -> sA ======
        ushort_t phv[M];
        ushort_t psv[M][4];
        #pragma unroll
        for (int m = 0; m < M; ++m) {
            phv[m] = phiB[(size_t)(p0+m)*C + ncol];
            #pragma unroll
            for (int r = 0; r < 4; ++r) {
                const int j = nidx[(size_t)(p0+m)*K + (kgrp<<2) + r];
                psv[m][r] = psiB[(size_t)j*C + ncol];
            }
        }

        f32x4 pos[M];
        #pragma unroll
        for (int m = 0; m < M; ++m) pos[m] = (f32x4){0.f,0.f,0.f,0.f};
        __builtin_amdgcn_s_setprio(1);
        #pragma unroll
        for (int m = 0; m < M; ++m)
            #pragma unroll
            for (int kk = 0; kk < 4; ++kk) {
                const int si = (((m<<4)+arow)<<7) + (((kk<<5)+krow0) ^ ((arow&7)<<3));
                pos[m] = mfma16(*(const f16x8*)&sT0[si], wd2[kk], pos[m]);
                pos[m] = mfma16(*(const f16x8*)&sT1[si], wd2[kk], pos[m]);
            }
        __builtin_amdgcn_s_setprio(0);

        #pragma unroll
        for (int m = 0; m < M; ++m) {
            #pragma unroll
            for (int z = 0; z < 4; ++z) pos[m][z] += bd2c;
            const float phic = f16tof(phv[m]);
            #pragma unroll
            for (int r = 0; r < 4; ++r) {
                const int row = (m<<4) + (kgrp<<2) + r;
                const float av = phic - f16tof(psv[m][r]) + pos[m][r];
                const u32 hv = ftof16(av);
                const u32 hp = (u32)__shfl_xor((int)hv, 1);
                if (!(lane&1)) {
                    const int si = (row<<7) + (ncol ^ ((row&7)<<3));
                    *(u32*)&sA[si] = hv | (hp<<16);
                }
            }
        }
        __syncthreads();                                        // S2

        // ======== phase 3: issue alpha loads; u = relu(attn@Wg1+bg1) -> sT1
        ushort_t alv[M][4];
        #pragma unroll
        for (int m = 0; m < M; ++m)
            #pragma unroll
            for (int r = 0; r < 4; ++r) {
                const int j = nidx[(size_t)(p0+m)*K + (kgrp<<2) + r];
                alv[m][r] = alfB[(size_t)j*C + ncol];
            }

        {
            f32x4 ua[M];
            #pragma unroll
            for (int m = 0; m < M; ++m) ua[m] = (f32x4){0.f,0.f,0.f,0.f};
            __builtin_amdgcn_s_setprio(1);
            #pragma unroll
            for (int m = 0; m < M; ++m)
                #pragma unroll
                for (int kk = 0; kk < 4; ++kk) {
                    const int si = (((m<<4)+arow)<<7) + (((kk<<5)+krow0) ^ ((arow&7)<<3));
                    ua[m] = mfma16(*(const f16x8*)&sA[si], wg1[kk], ua[m]);
                }
            __builtin_amdgcn_s_setprio(0);
            #pragma unroll
            for (int m = 0; m < M; ++m)
                #pragma unroll
                for (int r = 0; r < 4; ++r) {
                    const int row = (m<<4) + (kgrp<<2) + r;
                    const u32 hv = ftof16(fmaxf(ua[m][r] + bg1c, 0.f));
                    const u32 hp = (u32)__shfl_xor((int)hv, 1);
                    if (!(lane&1)) {
                        const int si = (row<<7) + (ncol ^ ((row&7)<<3));
                        *(u32*)&sT1[si] = hv | (hp<<16);
                    }
                }
        }
        // prefetch next group's t1 inputs
        if (hn) {
            const int pt = (g+1)*M + gpt;
            jP  = nidx[(size_t)pt*K + gk];
            cn0 = coords[(size_t)pt*3+0]; cn1 = coords[(size_t)pt*3+1]; cn2 = coords[(size_t)pt*3+2];
            cj0 = coords[(size_t)jP*3+0]; cj1 = coords[(size_t)jP*3+1]; cj2 = coords[(size_t)jP*3+2];
        }
        __syncthreads();                                        // S3

        // ======== phase 4: logits = u@Wg2; softmax; y -> sY ========
        f32x4 lg[M];
        #pragma unroll
        for (int m = 0; m < M; ++m) lg[m] = (f32x4){0.f,0.f,0.f,0.f};
        __builtin_amdgcn_s_setprio(1);
        #pragma unroll
        for (int m = 0; m < M; ++m)
            #pragma unroll
            for (int kk = 0; kk < 4; ++kk) {
                const int si = (((m<<4)+arow)<<7) + (((kk<<5)+krow0) ^ ((arow&7)<<3));
                lg[m] = mfma16(*(const f16x8*)&sT1[si], wg2[kk], lg[m]);
            }
        __builtin_amdgcn_s_setprio(0);

        #pragma unroll
        for (int m = 0; m < M; ++m) {
            float mx = fmaxf(fmaxf(lg[m][0], lg[m][1]), fmaxf(lg[m][2], lg[m][3]));
            mx = fmaxf(mx, __shfl_xor(mx, 16));
            mx = fmaxf(mx, __shfl_xor(mx, 32));
            const float e0 = __expf(lg[m][0]-mx), e1 = __expf(lg[m][1]-mx);
            const float e2 = __expf(lg[m][2]-mx), e3 = __expf(lg[m][3]-mx);
            float den = e0 + e1 + e2 + e3;
            den += __shfl_xor(den, 16);
            den += __shfl_xor(den, 32);
            const float inv = 1.0f / den;
            float yp;
            yp  = e0 * (f16tof(alv[m][0]) + pos[m][0]);
            yp += e1 * (f16tof(alv[m][1]) + pos[m][1]);
            yp += e2 * (f16tof(alv[m][2]) + pos[m][2]);
            yp += e3 * (f16tof(alv[m][3]) + pos[m][3]);
            yp *= inv;
            yp += __shfl_xor(yp, 16);
            yp += __shfl_xor(yp, 32);
            if (lane < 16) sY[m][ncol] = yp;
        }
        __syncthreads();                                        // S4

        // ======== phase 5: out = y @ W_down + b_down + x ========
        #pragma unroll
        for (int m = 0; m < M; ++m) {
            float acc = 0.f;
            const int e0i = kgrp << 5;
            #pragma unroll
            for (int z = 0; z < 4; ++z) {
                const float4 ya = *(const float4*)&sY[m][e0i + (z<<3)];
                const float4 yb = *(const float4*)&sY[m][e0i + (z<<3) + 4];
                const f16x8 w8 = wdn[z];
                acc = fmaf(ya.x, (float)w8[0], acc);
                acc = fmaf(ya.y, (float)w8[1], acc);
                acc = fmaf(ya.z, (float)w8[2], acc);
                acc = fmaf(ya.w, (float)w8[3], acc);
                acc = fmaf(yb.x, (float)w8[4], acc);
                acc = fmaf(yb.y, (float)w8[5], acc);
                acc = fmaf(yb.z, (float)w8[6], acc);
                acc = fmaf(yb.w, (float)w8[7], acc);
            }
            acc += __shfl_xor(acc, 16);
            acc += __shfl_xor(acc, 32);
            if (lane < 16) {
                const size_t p = (size_t)(p0 + m);
                out[p*C + ncol] = acc + bdnc + x[p*C + ncol];
            }
        }
    }
}

// ---------------------------------------------------------------------------
extern "C" void kernel_launch(void* const* d_in, const int* in_sizes, int n_in,
                              void* d_out, int out_size, void* d_ws, size_t ws_size,
                              hipStream_t stream)
{
    const float* x      = (const float*)d_in[0];
    const float* coords = (const float*)d_in[1];
    const int*   nidx   = (const int*)d_in[2];
    const float* W_top  = (const float*)d_in[3];
    const float* b_top  = (const float*)d_in[4];
    const float* W_down = (const float*)d_in[5];
    const float* b_down = (const float*)d_in[6];
    const float* W_phi  = (const float*)d_in[7];
    const float* b_phi  = (const float*)d_in[8];
    const float* W_psi  = (const float*)d_in[9];
    const float* b_psi  = (const float*)d_in[10];
    const float* W_alpha= (const float*)d_in[11];
    const float* b_alpha= (const float*)d_in[12];
    const float* W_d1   = (const float*)d_in[13];
    const float* b_d1   = (const float*)d_in[14];
    const float* W_d2   = (const float*)d_in[15];
    const float* b_d2   = (const float*)d_in[16];
    const float* W_g1   = (const float*)d_in[17];
    const float* b_g1   = (const float*)d_in[18];
    const float* W_g2   = (const float*)d_in[19];
    const float* b_g2   = (const float*)d_in[20];
    (void)b_g2; // softmax shift-invariant

    const int N = in_sizes[0] / C;

    ushort_t* WTt  = (ushort_t*)d_ws;
    ushort_t* WTp  = WTt  + C*C;
    ushort_t* WTs  = WTp  + C*C;
    ushort_t* WTa  = WTs  + C*C;
    ushort_t* WTd2 = WTa  + C*C;
    ushort_t* WTg1 = WTd2 + C*C;
    ushort_t* WTg2 = WTg1 + C*C;
    ushort_t* WTdn = WTg2 + C*C;
    ushort_t* phiB = WTdn + C*C;
    ushort_t* psiB = phiB + (size_t)N*C;
    ushort_t* alfB = psiB + (size_t)N*C;
    float* out = (float*)d_out;

    hipLaunchKernelGGL(k_prep, dim3(4*C), dim3(C), 0, stream,
        W_top, W_phi, W_psi, W_alpha, WTt, WTp, WTs, WTa);
    hipLaunchKernelGGL(k_prep, dim3(4*C), dim3(C), 0, stream,
        W_d2, W_g1, W_g2, W_down, WTd2, WTg1, WTg2, WTdn);

    hipLaunchKernelGGL(k_qkv2, dim3(N / 64), dim3(512), 0, stream,
        x, WTt, b_top, WTp, b_phi, WTs, b_psi, WTa, b_alpha,
        phiB, psiB, alfB);

    const int ngroups = N / M;                 // 16384
    const int NBLK = 2048;
    const int gpb = (ngroups + NBLK - 1) / NBLK;
    hipLaunchKernelGGL(k_attn5, dim3(NBLK), dim3(512), 0, stream,
        phiB, psiB, alfB, coords, nidx,
        W_d1, b_d1, WTd2, b_d2, WTg1, b_g1, WTg2,
        WTdn, b_down, x, out, ngroups, gpb);
}

// Round 7
// 542.178 us; speedup vs baseline: 1.9310x; 1.1700x over previous
//
#include <hip/hip_runtime.h>
#include <math.h>

#define C 128
#define K 16
#define M 4              // points per group
#define ROWS 64          // M*K rows per tile

typedef unsigned short ushort_t;
typedef unsigned int u32;
typedef float f32x4 __attribute__((ext_vector_type(4)));
typedef _Float16 f16x8 __attribute__((ext_vector_type(8)));

union U8h { _Float16 h[8]; uint4 u; };

__device__ __forceinline__ float f16tof(ushort_t b) {
    _Float16 h = __builtin_bit_cast(_Float16, b); return (float)h;
}
__device__ __forceinline__ ushort_t ftof16(float f) {
    _Float16 h = (_Float16)f; return __builtin_bit_cast(ushort_t, h);
}
__device__ __forceinline__ f32x4 mfma16(f16x8 a, f16x8 b, f32x4 c) {
    return __builtin_amdgcn_mfma_f32_16x16x32_f16(a, b, c, 0, 0, 0);
}

// ---------------------------------------------------------------------------
// Prep: transpose+convert 4 weight matrices fp32 -> fp16, WT[n][e] layout.
// ---------------------------------------------------------------------------
__global__ __launch_bounds__(128) void k_prep(
    const float* __restrict__ s0, const float* __restrict__ s1,
    const float* __restrict__ s2, const float* __restrict__ s3,
    ushort_t* __restrict__ d0, ushort_t* __restrict__ d1,
    ushort_t* __restrict__ d2, ushort_t* __restrict__ d3)
{
    const int m = blockIdx.x >> 7, n = blockIdx.x & 127, e = threadIdx.x;
    const float* s = (m==0) ? s0 : (m==1) ? s1 : (m==2) ? s2 : s3;
    ushort_t*   d = (m==0) ? d0 : (m==1) ? d1 : (m==2) ? d2 : d3;
    d[n*C + e] = ftof16(s[e*C + n]);
}

// ---------------------------------------------------------------------------
// Kernel 1: h = x@W_top + b; phi/psi/alpha = h@W_* + b   via f16 MFMA.
// ---------------------------------------------------------------------------
__global__ __launch_bounds__(512) void k_qkv2(
    const float* __restrict__ x,
    const ushort_t* __restrict__ WTt, const float* __restrict__ bt,
    const ushort_t* __restrict__ WTp, const float* __restrict__ bp,
    const ushort_t* __restrict__ WTs, const float* __restrict__ bs,
    const ushort_t* __restrict__ WTa, const float* __restrict__ ba,
    ushort_t* __restrict__ phiB, ushort_t* __restrict__ psiB,
    ushort_t* __restrict__ alfB)
{
    __shared__ ushort_t sX[64*C];
    __shared__ ushort_t sH[64*C];
    const int tid = threadIdx.x, lane = tid & 63, wv = tid >> 6;
    const int ncol = (wv<<4) + (lane&15), arow = lane&15;
    const int kgrp = lane>>4, krow0 = kgrp<<3;
    const int r0 = blockIdx.x * 64;

    {
        const int rX = tid>>3, cX = (tid&7)<<4;
        const float* xp = &x[(size_t)(r0+rX)*C + cX];
        #pragma unroll
        for (int hf = 0; hf < 2; ++hf) {
            const float4 a  = *(const float4*)&xp[hf*8 + 0];
            const float4 b2 = *(const float4*)&xp[hf*8 + 4];
            U8h v;
            v.h[0]=(_Float16)a.x;  v.h[1]=(_Float16)a.y;
            v.h[2]=(_Float16)a.z;  v.h[3]=(_Float16)a.w;
            v.h[4]=(_Float16)b2.x; v.h[5]=(_Float16)b2.y;
            v.h[6]=(_Float16)b2.z; v.h[7]=(_Float16)b2.w;
            const int col = cX + hf*8;
            *(uint4*)&sX[(rX<<7) + (col ^ ((rX&7)<<3))] = v.u;
        }
    }
    __syncthreads();

    {
        f16x8 bf[4]; f32x4 hacc[4];
        #pragma unroll
        for (int kk = 0; kk < 4; ++kk)
            bf[kk] = *(const f16x8*)&WTt[(size_t)ncol*C + (kk<<5) + krow0];
        #pragma unroll
        for (int m = 0; m < 4; ++m) hacc[m] = (f32x4){0.f,0.f,0.f,0.f};
        __builtin_amdgcn_s_setprio(1);
        #pragma unroll
        for (int m = 0; m < 4; ++m)
            #pragma unroll
            for (int kk = 0; kk < 4; ++kk) {
                const int row = (m<<4) + arow;
                const f16x8 af = *(const f16x8*)&sX[(row<<7) + (((kk<<5)+krow0) ^ ((arow&7)<<3))];
                hacc[m] = mfma16(af, bf[kk], hacc[m]);
            }
        __builtin_amdgcn_s_setprio(0);
        const float btc = bt[ncol];
        #pragma unroll
        for (int m = 0; m < 4; ++m)
            #pragma unroll
            for (int r = 0; r < 4; ++r) {
                const int row = (m<<4) + (kgrp<<2) + r;
                sH[(row<<7) + (ncol ^ ((row&7)<<3))] = ftof16(hacc[m][r] + btc);
            }
    }
    __syncthreads();

#define OGEMM(WT_, b_, o_)                                                    \
    {                                                                         \
        f16x8 wf[4]; f32x4 oacc[4];                                           \
        _Pragma("unroll")                                                     \
        for (int kk = 0; kk < 4; ++kk)                                        \
            wf[kk] = *(const f16x8*)&WT_[(size_t)ncol*C + (kk<<5) + krow0];   \
        _Pragma("unroll")                                                     \
        for (int m = 0; m < 4; ++m) oacc[m] = (f32x4){0.f,0.f,0.f,0.f};      \
        __builtin_amdgcn_s_setprio(1);                                        \
        _Pragma("unroll")                                                     \
        for (int m = 0; m < 4; ++m)                                           \
            _Pragma("unroll")                                                 \
            for (int kk = 0; kk < 4; ++kk) {                                  \
                const int row = (m<<4) + arow;                                \
                const f16x8 af = *(const f16x8*)&sH[(row<<7) + (((kk<<5)+krow0) ^ ((arow&7)<<3))]; \
                oacc[m] = mfma16(af, wf[kk], oacc[m]);                        \
            }                                                                 \
        __builtin_amdgcn_s_setprio(0);                                        \
        const float bc = b_[ncol];                                            \
        _Pragma("unroll")                                                     \
        for (int m = 0; m < 4; ++m)                                           \
            _Pragma("unroll")                                                 \
            for (int r = 0; r < 4; ++r) {                                     \
                const int row = (m<<4) + (kgrp<<2) + r;                       \
                o_[(size_t)(r0+row)*C + ncol] = ftof16(oacc[m][r] + bc);      \
            }                                                                 \
    }
    OGEMM(WTp, bp, phiB)
    OGEMM(WTs, bs, psiB)
    OGEMM(WTa, ba, alfB)
#undef OGEMM
}

// ---------------------------------------------------------------------------
// Kernel 2: fused vector attention -> yB (f16). Register-trimmed for
// 2 blocks/CU: no W_down, wg2 streamed from global, scalar b16 LDS writes.
// ---------------------------------------------------------------------------
__global__ __launch_bounds__(512, 4) void k_attn6(
    const ushort_t* __restrict__ phiB, const ushort_t* __restrict__ psiB,
    const ushort_t* __restrict__ alfB,
    const float* __restrict__ coords, const int* __restrict__ nidx,
    const float* __restrict__ Wd1, const float* __restrict__ bd1,
    const ushort_t* __restrict__ WTd2, const float* __restrict__ bd2,
    const ushort_t* __restrict__ WTg1, const float* __restrict__ bg1,
    const ushort_t* __restrict__ WTg2,
    ushort_t* __restrict__ yB,
    int ngroups, int gpb)
{
    __shared__ ushort_t sT0[ROWS*C];   // t1 hi
    __shared__ ushort_t sT1[ROWS*C];   // t1 lo, then u
    __shared__ ushort_t sA[ROWS*C];    // attn (single f16)
    __shared__ float    sWd1[3][C];
    __shared__ float    sbd1v[C];

    const int tid  = threadIdx.x, lane = tid & 63, wv = tid >> 6;
    const int ncol = (wv<<4) + (lane&15);
    const int arow = lane & 15;
    const int kgrp = lane >> 4, krow0 = kgrp << 3;
    const int grow = tid >> 3;            // t1 row 0..63
    const int gpt  = grow >> 4;           // point-in-group 0..3
    const int gk   = grow & 15;           // neighbor 0..15
    const int gc   = (tid & 7) << 4;      // 16-ch slice base

    const int g0 = blockIdx.x * gpb;
    if (g0 >= ngroups) return;
    const int gend = (g0 + gpb < ngroups) ? (g0 + gpb) : ngroups;

    if (tid < 3*C) ((float*)sWd1)[tid] = Wd1[tid];
    else if (tid < 4*C) sbd1v[tid - 3*C] = bd1[tid - 3*C];

    // persistent weight fragments: wd2 + wg1 only (32 VGPR)
    f16x8 wd2[4], wg1[4];
    #pragma unroll
    for (int kk = 0; kk < 4; ++kk) {
        wd2[kk] = *(const f16x8*)&WTd2[(size_t)ncol*C + (kk<<5) + krow0];
        wg1[kk] = *(const f16x8*)&WTg1[(size_t)ncol*C + (kk<<5) + krow0];
    }
    const float bd2c = bd2[ncol], bg1c = bg1[ncol];

    __syncthreads();   // sWd1 staged

    // prologue prefetch (t1 inputs for group g0, grow layout)
    int jP; float cn0,cn1,cn2,cj0,cj1,cj2;
    {
        const int pt = g0*M + gpt;
        jP  = nidx[(size_t)pt*K + gk];
        cn0 = coords[(size_t)pt*3+0]; cn1 = coords[(size_t)pt*3+1]; cn2 = coords[(size_t)pt*3+2];
        cj0 = coords[(size_t)jP*3+0]; cj1 = coords[(size_t)jP*3+1]; cj2 = coords[(size_t)jP*3+2];
    }

    const int si0 = (grow<<7) + (gc ^ ((grow&7)<<3));
    const int si1 = (grow<<7) + ((gc+8) ^ ((grow&7)<<3));

    for (int g = g0; g < gend; ++g) {
        const int p0 = g * M;
        const bool hn = (g + 1 < gend);

        // ======== phase 1: t1 = relu(rel@Wd1+bd1), hi/lo -> sT0/sT1 ========
        {
            const float rx = cn0 - cj0, ry = cn1 - cj1, rz = cn2 - cj2;
            #pragma unroll
            for (int hf = 0; hf < 2; ++hf) {
                U8h hi, lo;
                #pragma unroll
                for (int z = 0; z < 8; ++z) {
                    const int c = gc + (hf<<3) + z;
                    float t = fmaf(rx, sWd1[0][c],
                              fmaf(ry, sWd1[1][c],
                              fmaf(rz, sWd1[2][c], sbd1v[c])));
                    t = fmaxf(t, 0.f);
                    hi.h[z] = (_Float16)t;
                    lo.h[z] = (_Float16)(t - (float)hi.h[z]);
                }
                const int si = hf ? si1 : si0;
                *(uint4*)&sT0[si] = hi.u;
                *(uint4*)&sT1[si] = lo.u;
            }
        }
        __syncthreads();                                        // S1

        // ======== phase 2: issue psi/phi loads; pos MFMA; attn -> sA ======
        ushort_t phv[M];
        ushort_t psv[M][4];
        #pragma unroll
        for (int m = 0; m < M; ++m) {
            phv[m] = phiB[(size_t)(p0+m)*C + ncol];
            const int4 j4 = *(const int4*)&nidx[(size_t)(p0+m)*K + (kgrp<<2)];
            psv[m][0] = psiB[(size_t)j4.x*C + ncol];
            psv[m][1] = psiB[(size_t)j4.y*C + ncol];
            psv[m][2] = psiB[(size_t)j4.z*C + ncol];
            psv[m][3] = psiB[(size_t)j4.w*C + ncol];
        }

        f32x4 pos[M];
        #pragma unroll
        for (int m = 0; m < M; ++m) pos[m] = (f32x4){0.f,0.f,0.f,0.f};
        __builtin_amdgcn_s_setprio(1);
        #pragma unroll
        for (int m = 0; m < M; ++m)
            #pragma unroll
            for (int kk = 0; kk < 4; ++kk) {
                const int si = (((m<<4)+arow)<<7) + (((kk<<5)+krow0) ^ ((arow&7)<<3));
                pos[m] = mfma16(*(const f16x8*)&sT0[si], wd2[kk], pos[m]);
                pos[m] = mfma16(*(const f16x8*)&sT1[si], wd2[kk], pos[m]);
            }
        __builtin_amdgcn_s_setprio(0);

        #pragma unroll
        for (int m = 0; m < M; ++m) {
            #pragma unroll
            for (int z = 0; z < 4; ++z) pos[m][z] += bd2c;
            const float phic = f16tof(phv[m]);
            #pragma unroll
            for (int r = 0; r < 4; ++r) {
                const int row = (m<<4) + (kgrp<<2) + r;
                const float av = phic - f16tof(psv[m][r]) + pos[m][r];
                sA[(row<<7) + (ncol ^ ((row&7)<<3))] = ftof16(av);
            }
        }
        __syncthreads();                                        // S2

        // ======== phase 3: issue alpha + wg2 loads; u = relu(attn@Wg1+bg1)
        ushort_t alv[M][4];
        #pragma unroll
        for (int m = 0; m < M; ++m) {
            const int4 j4 = *(const int4*)&nidx[(size_t)(p0+m)*K + (kgrp<<2)];
            alv[m][0] = alfB[(size_t)j4.x*C + ncol];
            alv[m][1] = alfB[(size_t)j4.y*C + ncol];
            alv[m][2] = alfB[(size_t)j4.z*C + ncol];
            alv[m][3] = alfB[(size_t)j4.w*C + ncol];
        }
        f16x8 wg2s[4];
        #pragma unroll
        for (int kk = 0; kk < 4; ++kk)
            wg2s[kk] = *(const f16x8*)&WTg2[(size_t)ncol*C + (kk<<5) + krow0];

        {
            f32x4 ua[M];
            #pragma unroll
            for (int m = 0; m < M; ++m) ua[m] = (f32x4){0.f,0.f,0.f,0.f};
            __builtin_amdgcn_s_setprio(1);
            #pragma unroll
            for (int m = 0; m < M; ++m)
                #pragma unroll
                for (int kk = 0; kk < 4; ++kk) {
                    const int si = (((m<<4)+arow)<<7) + (((kk<<5)+krow0) ^ ((arow&7)<<3));
                    ua[m] = mfma16(*(const f16x8*)&sA[si], wg1[kk], ua[m]);
                }
            __builtin_amdgcn_s_setprio(0);
            #pragma unroll
            for (int m = 0; m < M; ++m)
                #pragma unroll
                for (int r = 0; r < 4; ++r) {
                    const int row = (m<<4) + (kgrp<<2) + r;
                    sT1[(row<<7) + (ncol ^ ((row&7)<<3))] =
                        ftof16(fmaxf(ua[m][r] + bg1c, 0.f));
                }
        }
        // prefetch next group's t1 inputs
        if (hn) {
            const int pt = (g+1)*M + gpt;
            jP  = nidx[(size_t)pt*K + gk];
            cn0 = coords[(size_t)pt*3+0]; cn1 = coords[(size_t)pt*3+1]; cn2 = coords[(size_t)pt*3+2];
            cj0 = coords[(size_t)jP*3+0]; cj1 = coords[(size_t)jP*3+1]; cj2 = coords[(size_t)jP*3+2];
        }
        __syncthreads();                                        // S3

        // ======== phase 4: logits = u@Wg2; softmax; y -> yB (f16) ========
        f32x4 lg[M];
        #pragma unroll
        for (int m = 0; m < M; ++m) lg[m] = (f32x4){0.f,0.f,0.f,0.f};
        __builtin_amdgcn_s_setprio(1);
        #pragma unroll
        for (int m = 0; m < M; ++m)
            #pragma unroll
            for (int kk = 0; kk < 4; ++kk) {
                const int si = (((m<<4)+arow)<<7) + (((kk<<5)+krow0) ^ ((arow&7)<<3));
                lg[m] = mfma16(*(const f16x8*)&sT1[si], wg2s[kk], lg[m]);
            }
        __builtin_amdgcn_s_setprio(0);

        #pragma unroll
        for (int m = 0; m < M; ++m) {
            float mx = fmaxf(fmaxf(lg[m][0], lg[m][1]), fmaxf(lg[m][2], lg[m][3]));
            mx = fmaxf(mx, __shfl_xor(mx, 16));
            mx = fmaxf(mx, __shfl_xor(mx, 32));
            const float e0 = __expf(lg[m][0]-mx), e1 = __expf(lg[m][1]-mx);
            const float e2 = __expf(lg[m][2]-mx), e3 = __expf(lg[m][3]-mx);
            float den = e0 + e1 + e2 + e3;
            den += __shfl_xor(den, 16);
            den += __shfl_xor(den, 32);
            const float inv = 1.0f / den;
            float yp;
            yp  = e0 * (f16tof(alv[m][0]) + pos[m][0]);
            yp += e1 * (f16tof(alv[m][1]) + pos[m][1]);
            yp += e2 * (f16tof(alv[m][2]) + pos[m][2]);
            yp += e3 * (f16tof(alv[m][3]) + pos[m][3]);
            yp *= inv;
            yp += __shfl_xor(yp, 16);
            yp += __shfl_xor(yp, 32);
            if (lane < 16)
                yB[(size_t)(p0+m)*C + ncol] = ftof16(yp);
        }
        __syncthreads();                                        // S4
    }
}

// ---------------------------------------------------------------------------
// Kernel 3: out = y @ W_down + b_down + x   (f16 MFMA GEMM, 64 rows/block)
// ---------------------------------------------------------------------------
__global__ __launch_bounds__(512) void k_down(
    const ushort_t* __restrict__ yB,
    const ushort_t* __restrict__ WTdn, const float* __restrict__ bdn,
    const float* __restrict__ x, float* __restrict__ out)
{
    __shared__ ushort_t sY[64*C];
    const int tid = threadIdx.x, lane = tid & 63, wv = tid >> 6;
    const int ncol = (wv<<4) + (lane&15), arow = lane&15;
    const int kgrp = lane>>4, krow0 = kgrp<<3;
    const int r0 = blockIdx.x * 64;

    {
        const int rY = tid>>3, cY = (tid&7)<<4;
        #pragma unroll
        for (int hf = 0; hf < 2; ++hf) {
            const uint4 v = *(const uint4*)&yB[(size_t)(r0+rY)*C + cY + hf*8];
            *(uint4*)&sY[(rY<<7) + ((cY + hf*8) ^ ((rY&7)<<3))] = v;
        }
    }
    __syncthreads();

    f16x8 wf[4]; f32x4 oacc[4];
    #pragma unroll
    for (int kk = 0; kk < 4; ++kk)
        wf[kk] = *(const f16x8*)&WTdn[(size_t)ncol*C + (kk<<5) + krow0];
    #pragma unroll
    for (int m = 0; m < 4; ++m) oacc[m] = (f32x4){0.f,0.f,0.f,0.f};
    __builtin_amdgcn_s_setprio(1);
    #pragma unroll
    for (int m = 0; m < 4; ++m)
        #pragma unroll
        for (int kk = 0; kk < 4; ++kk) {
            const int row = (m<<4) + arow;
            const f16x8 af = *(const f16x8*)&sY[(row<<7) + (((kk<<5)+krow0) ^ ((arow&7)<<3))];
            oacc[m] = mfma16(af, wf[kk], oacc[m]);
        }
    __builtin_amdgcn_s_setprio(0);
    const float bc = bdn[ncol];
    #pragma unroll
    for (int m = 0; m < 4; ++m)
        #pragma unroll
        for (int r = 0; r < 4; ++r) {
            const int row = (m<<4) + (kgrp<<2) + r;
            const size_t idx = (size_t)(r0+row)*C + ncol;
            out[idx] = oacc[m][r] + bc + x[idx];
        }
}

// ---------------------------------------------------------------------------
extern "C" void kernel_launch(void* const* d_in, const int* in_sizes, int n_in,
                              void* d_out, int out_size, void* d_ws, size_t ws_size,
                              hipStream_t stream)
{
    const float* x      = (const float*)d_in[0];
    const float* coords = (const float*)d_in[1];
    const int*   nidx   = (const int*)d_in[2];
    const float* W_top  = (const float*)d_in[3];
    const float* b_top  = (const float*)d_in[4];
    const float* W_down = (const float*)d_in[5];
    const float* b_down = (const float*)d_in[6];
    const float* W_phi  = (const float*)d_in[7];
    const float* b_phi  = (const float*)d_in[8];
    const float* W_psi  = (const float*)d_in[9];
    const float* b_psi  = (const float*)d_in[10];
    const float* W_alpha= (const float*)d_in[11];
    const float* b_alpha= (const float*)d_in[12];
    const float* W_d1   = (const float*)d_in[13];
    const float* b_d1   = (const float*)d_in[14];
    const float* W_d2   = (const float*)d_in[15];
    const float* b_d2   = (const float*)d_in[16];
    const float* W_g1   = (const float*)d_in[17];
    const float* b_g1   = (const float*)d_in[18];
    const float* W_g2   = (const float*)d_in[19];
    const float* b_g2   = (const float*)d_in[20];
    (void)b_g2; // softmax shift-invariant

    const int N = in_sizes[0] / C;

    ushort_t* WTt  = (ushort_t*)d_ws;
    ushort_t* WTp  = WTt  + C*C;
    ushort_t* WTs  = WTp  + C*C;
    ushort_t* WTa  = WTs  + C*C;
    ushort_t* WTd2 = WTa  + C*C;
    ushort_t* WTg1 = WTd2 + C*C;
    ushort_t* WTg2 = WTg1 + C*C;
    ushort_t* WTdn = WTg2 + C*C;
    ushort_t* phiB = WTdn + C*C;
    ushort_t* psiB = phiB + (size_t)N*C;
    ushort_t* alfB = psiB + (size_t)N*C;
    ushort_t* yB   = alfB + (size_t)N*C;
    float* out = (float*)d_out;

    hipLaunchKernelGGL(k_prep, dim3(4*C), dim3(C), 0, stream,
        W_top, W_phi, W_psi, W_alpha, WTt, WTp, WTs, WTa);
    hipLaunchKernelGGL(k_prep, dim3(4*C), dim3(C), 0, stream,
        W_d2, W_g1, W_g2, W_down, WTd2, WTg1, WTg2, WTdn);

    hipLaunchKernelGGL(k_qkv2, dim3(N / 64), dim3(512), 0, stream,
        x, WTt, b_top, WTp, b_phi, WTs, b_psi, WTa, b_alpha,
        phiB, psiB, alfB);

    const int ngroups = N / M;                 // 16384
    const int NBLK = 2048;
    const int gpb = (ngroups + NBLK - 1) / NBLK;
    hipLaunchKernelGGL(k_attn6, dim3(NBLK), dim3(512), 0, stream,
        phiB, psiB, alfB, coords, nidx,
        W_d1, b_d1, WTd2, b_d2, WTg1, b_g1, WTg2,
        yB, ngroups, gpb);

    hipLaunchKernelGGL(k_down, dim3(N / 64), dim3(512), 0, stream,
        yB, WTdn, b_down, x, out);
}